// Round 1
// baseline (3132.712 us; speedup 1.0000x reference)
//
#include <hip/hip_runtime.h>
#include <math.h>

#define SEQ 5
#define D 64

// ---------- wave helpers ----------
__device__ __forceinline__ float bcast(float x, int i) {
  return __int_as_float(__builtin_amdgcn_readlane(__float_as_int(x), i));
}
__device__ __forceinline__ float wred64(float x) {
#pragma unroll
  for (int off = 32; off; off >>= 1) x += __shfl_xor(x, off);
  return x;
}
__device__ __forceinline__ float hred8(float x) {
  x += __shfl_xor(x, 1);
  x += __shfl_xor(x, 2);
  x += __shfl_xor(x, 4);
  return x;
}
__device__ __forceinline__ float lnorm(float t, const float* __restrict__ g,
                                       const float* __restrict__ b, int lane) {
  float m = wred64(t) * (1.0f / 64.0f);
  float c = t - m;
  float v = wred64(c * c) * (1.0f / 64.0f);
  return c * rsqrtf(v + 1e-5f) * g[lane] + b[lane];
}
__device__ __forceinline__ float gelu(float x) {
  return 0.5f * x * (1.0f + erff(x * 0.70710678118654752440f));
}
// monotonic unsigned key encoding for float atomicMax
__device__ __forceinline__ unsigned int fkey(float f) {
  unsigned int b = __float_as_uint(f);
  return (b & 0x80000000u) ? ~b : (b | 0x80000000u);
}
__device__ __forceinline__ float funkey(unsigned int k) {
  return __uint_as_float((k & 0x80000000u) ? (k ^ 0x80000000u) : ~k);
}

// ---------- zero fill ----------
__global__ void zero_kernel(float4* __restrict__ p, int n4) {
  int t = blockIdx.x * blockDim.x + threadIdx.x;
  if (t < n4) p[t] = make_float4(0.f, 0.f, 0.f, 0.f);
}

// ---------- transpose all weight matrices into d_ws ----------
// layout (element offsets, dst T[i][j] = src[j][i], i = input dim):
//   T_si  @ 0      [64][192]   self_in_w  (192x64)
//   T_so  @ 12288  [64][64]    self_out_w (64x64)
//   T_w1s @ 16384  [64][256]   sa_ff_w1   (256x64)
//   T_w2s @ 32768  [256][64]   sa_ff_w2   (64x256)
//   T_ci  @ 49152  [64][192]   cross_in_w
//   T_co  @ 61440  [64][64]    cross_out_w
//   T_w1c @ 65536  [64][256]   ca_ff_w1
//   T_w2c @ 81920  [256][64]   ca_ff_w2
//   T_iw  @ 98304  [64][512]   inst_w     (512x64)
__global__ void transpose_kernel(const float* __restrict__ si, const float* __restrict__ so,
                                 const float* __restrict__ w1s, const float* __restrict__ w2s,
                                 const float* __restrict__ ci, const float* __restrict__ co,
                                 const float* __restrict__ w1c, const float* __restrict__ w2c,
                                 const float* __restrict__ iw, float* __restrict__ wT) {
  int t = blockIdx.x * blockDim.x + threadIdx.x;
  const float* src;
  int base, R, cs;  // cs = log2(C)
  if      (t < 12288)  { src = si;  base = 0;     R = 192; cs = 6; }
  else if (t < 16384)  { src = so;  base = 12288; R = 64;  cs = 6; }
  else if (t < 32768)  { src = w1s; base = 16384; R = 256; cs = 6; }
  else if (t < 49152)  { src = w2s; base = 32768; R = 64;  cs = 8; }
  else if (t < 61440)  { src = ci;  base = 49152; R = 192; cs = 6; }
  else if (t < 65536)  { src = co;  base = 61440; R = 64;  cs = 6; }
  else if (t < 81920)  { src = w1c; base = 65536; R = 256; cs = 6; }
  else if (t < 98304)  { src = w2c; base = 81920; R = 64;  cs = 8; }
  else if (t < 131072) { src = iw;  base = 98304; R = 512; cs = 6; }
  else return;
  int l = t - base;
  int j = l >> cs;
  int i = l & ((1 << cs) - 1);
  wT[base + i * R + j] = src[l];
}

// ---------- FF block: x(LNed, per-lane) -> 256 hidden (gelu) -> 64 out ----------
__device__ __forceinline__ float ffn_block(float xln, int lane,
                                           const float* __restrict__ T1,
                                           const float* __restrict__ T2,
                                           const float* __restrict__ b1,
                                           const float* __restrict__ b2) {
  float h0 = b1[lane], h1 = b1[64 + lane], h2 = b1[128 + lane], h3 = b1[192 + lane];
#pragma unroll 4
  for (int i = 0; i < 64; i++) {
    float xi = bcast(xln, i);
    const float* w = T1 + i * 256 + lane;
    h0 = fmaf(xi, w[0], h0);
    h1 = fmaf(xi, w[64], h1);
    h2 = fmaf(xi, w[128], h2);
    h3 = fmaf(xi, w[192], h3);
  }
  h0 = gelu(h0); h1 = gelu(h1); h2 = gelu(h2); h3 = gelu(h3);
  float out = b2[lane];
#pragma unroll 4
  for (int i = 0; i < 64; i++) {
    const float* w = T2 + i * 64 + lane;  // hidden j = r*64+i -> T2[j*64+lane]
    out = fmaf(bcast(h0, i), w[0], out);
    out = fmaf(bcast(h1, i), w[4096], out);
    out = fmaf(bcast(h2, i), w[8192], out);
    out = fmaf(bcast(h3, i), w[12288], out);
  }
  return out;
}

// ---------- the per-edge transformer (one wave per edge, lane = channel) ----------
__global__ __launch_bounds__(256)
void edge_kernel(const float* __restrict__ features, const float* __restrict__ pos_emb,
                 const float* __restrict__ self_in_b, const float* __restrict__ self_out_b,
                 const float* __restrict__ cross_in_b, const float* __restrict__ cross_out_b,
                 const float* __restrict__ sa_ln1_g, const float* __restrict__ sa_ln1_b,
                 const float* __restrict__ sa_ln2_g, const float* __restrict__ sa_ln2_b,
                 const float* __restrict__ ca_ln1_g, const float* __restrict__ ca_ln1_b,
                 const float* __restrict__ ca_ln2_g, const float* __restrict__ ca_ln2_b,
                 const float* __restrict__ sa_ff_b1, const float* __restrict__ sa_ff_b2,
                 const float* __restrict__ ca_ff_b1, const float* __restrict__ ca_ff_b2,
                 const float* __restrict__ attn_vec,
                 const int* __restrict__ midx, const int* __restrict__ dstv,
                 const float* __restrict__ wT,
                 float* __restrict__ inst_out, float* __restrict__ a_out,
                 unsigned int* __restrict__ seg_max, int E, int N) {
  const int wid = (blockIdx.x * blockDim.x + threadIdx.x) >> 6;
  const int lane = threadIdx.x & 63;
  if (wid >= E) return;

  const float* T_si  = wT;
  const float* T_so  = wT + 12288;
  const float* T_w1s = wT + 16384;
  const float* T_w2s = wT + 32768;
  const float* T_ci  = wT + 49152;
  const float* T_co  = wT + 61440;
  const float* T_w1c = wT + 65536;
  const float* T_w2c = wT + 81920;
  const float* T_iw  = wT + 98304;

  int ids[SEQ];
  bool val[SEQ];
#pragma unroll
  for (int s = 0; s < SEQ; s++) {
    ids[s] = midx[wid * SEQ + s];
    val[s] = ids[s] != N;  // pad row id == N
  }

  // gather + positional embedding (pos zeroed at padded positions; pad row is zero)
  float tok[SEQ];
#pragma unroll
  for (int s = 0; s < SEQ; s++)
    tok[s] = val[s] ? features[ids[s] * D + lane] + pos_emb[s * D + lane] : 0.0f;

  // ---- self-attention (pre-LN) ----
  float x[SEQ];
#pragma unroll
  for (int s = 0; s < SEQ; s++) x[s] = lnorm(tok[s], sa_ln1_g, sa_ln1_b, lane);

  float q[SEQ], k[SEQ], v[SEQ];
#pragma unroll
  for (int s = 0; s < SEQ; s++) {
    q[s] = self_in_b[lane];
    k[s] = self_in_b[64 + lane];
    v[s] = self_in_b[128 + lane];
  }
#pragma unroll 4
  for (int i = 0; i < 64; i++) {
    const float* w = T_si + i * 192 + lane;
    float wq = w[0], wk = w[64], wv = w[128];
#pragma unroll
    for (int s = 0; s < SEQ; s++) {
      float xi = bcast(x[s], i);
      q[s] = fmaf(xi, wq, q[s]);
      k[s] = fmaf(xi, wk, k[s]);
      v[s] = fmaf(xi, wv, v[s]);
    }
  }

  const float scale = 0.35355339059327373f;  // 1/sqrt(dh=8)
  float att[SEQ][SEQ];
#pragma unroll
  for (int qs = 0; qs < SEQ; qs++) {
#pragma unroll
    for (int ks = 0; ks < SEQ; ks++) {
      float p = hred8(q[qs] * k[ks]) * scale;  // per-head dot (8-lane groups)
      att[qs][ks] = val[ks] ? p : -1e9f;
    }
    float m = att[qs][0];
#pragma unroll
    for (int ks = 1; ks < SEQ; ks++) m = fmaxf(m, att[qs][ks]);
    float sum = 0.f;
#pragma unroll
    for (int ks = 0; ks < SEQ; ks++) {
      att[qs][ks] = __expf(att[qs][ks] - m);
      sum += att[qs][ks];
    }
    float r = 1.0f / sum;
#pragma unroll
    for (int ks = 0; ks < SEQ; ks++) att[qs][ks] *= r;
  }

  float o[SEQ];
#pragma unroll
  for (int qs = 0; qs < SEQ; qs++) {
    float acc = 0.f;
#pragma unroll
    for (int ks = 0; ks < SEQ; ks++) acc = fmaf(att[qs][ks], v[ks], acc);
    o[qs] = acc;
  }

  float y[SEQ];
#pragma unroll
  for (int s = 0; s < SEQ; s++) y[s] = self_out_b[lane];
#pragma unroll 4
  for (int i = 0; i < 64; i++) {
    float w = T_so[i * 64 + lane];
#pragma unroll
    for (int s = 0; s < SEQ; s++) y[s] = fmaf(bcast(o[s], i), w, y[s]);
  }
#pragma unroll
  for (int s = 0; s < SEQ; s++) tok[s] += y[s];

  // ---- masked mean pool ----
  float nv = 0.f, inst = 0.f;
#pragma unroll
  for (int s = 0; s < SEQ; s++)
    if (val[s]) { nv += 1.f; inst += tok[s]; }
  inst /= fmaxf(nv, 1.0f);

  // ---- sa FF ----
  inst += ffn_block(lnorm(inst, sa_ln2_g, sa_ln2_b, lane), lane, T_w1s, T_w2s, sa_ff_b1, sa_ff_b2);

  // ---- cross attention: LN(last-node feat) attends over post-SA tokens ----
  int lp = (int)nv - 1;
  if (lp < 0) lp = 0;
  int lid = midx[wid * SEQ + lp];
  float tf = (lid != N) ? features[lid * D + lane] : 0.0f;
  float qx = lnorm(tf, ca_ln1_g, ca_ln1_b, lane);

  float q2 = cross_in_b[lane];
  float k2[SEQ], v2[SEQ];
#pragma unroll
  for (int s = 0; s < SEQ; s++) {
    k2[s] = cross_in_b[64 + lane];
    v2[s] = cross_in_b[128 + lane];
  }
#pragma unroll 4
  for (int i = 0; i < 64; i++) {
    const float* w = T_ci + i * 192 + lane;
    float wq = w[0], wk = w[64], wv = w[128];
    q2 = fmaf(bcast(qx, i), wq, q2);
#pragma unroll
    for (int s = 0; s < SEQ; s++) {
      float ti = bcast(tok[s], i);  // k/v input is raw post-SA tokens (no LN)
      k2[s] = fmaf(ti, wk, k2[s]);
      v2[s] = fmaf(ti, wv, v2[s]);
    }
  }
  float sc[SEQ];
#pragma unroll
  for (int s = 0; s < SEQ; s++) {
    float p = hred8(q2 * k2[s]) * scale;
    sc[s] = val[s] ? p : -1e9f;
  }
  float m2 = sc[0];
#pragma unroll
  for (int s = 1; s < SEQ; s++) m2 = fmaxf(m2, sc[s]);
  float sum2 = 0.f;
#pragma unroll
  for (int s = 0; s < SEQ; s++) {
    sc[s] = __expf(sc[s] - m2);
    sum2 += sc[s];
  }
  float r2 = 1.0f / sum2;
  float o2 = 0.f;
#pragma unroll
  for (int s = 0; s < SEQ; s++) o2 = fmaf(sc[s] * r2, v2[s], o2);

  float y2 = cross_out_b[lane];
#pragma unroll 4
  for (int i = 0; i < 64; i++) y2 = fmaf(bcast(o2, i), T_co[i * 64 + lane], y2);
  inst += y2;

  // ---- ca FF ----
  inst += ffn_block(lnorm(inst, ca_ln2_g, ca_ln2_b, lane), lane, T_w1c, T_w2c, ca_ff_b1, ca_ff_b2);

  inst_out[wid * D + lane] = inst;

  // ---- eft (heads proj) + leaky-relu score + seg_max atomic ----
  float ef[8];
#pragma unroll
  for (int r = 0; r < 8; r++) ef[r] = 0.f;
#pragma unroll 4
  for (int i = 0; i < 64; i++) {
    float xi = bcast(inst, i);
    const float* w = T_iw + i * 512 + lane;
#pragma unroll
    for (int r = 0; r < 8; r++) ef[r] = fmaf(xi, w[r * 64], ef[r]);
  }
  int dd = dstv[wid];
#pragma unroll
  for (int r = 0; r < 8; r++) {
    float ar = wred64(ef[r] * attn_vec[r * 64 + lane]);
    ar = ar > 0.f ? ar : 0.01f * ar;  // leaky relu
    if (lane == r) {
      a_out[wid * 8 + r] = ar;
      atomicMax(&seg_max[dd * 8 + r], fkey(ar));
    }
  }
}

// ---------- edge softmax denominator ----------
__global__ void expsum_kernel(const float* __restrict__ a, const int* __restrict__ dstv,
                              const unsigned int* __restrict__ seg_max,
                              float* __restrict__ seg_sum, int E8) {
  int t = blockIdx.x * blockDim.x + threadIdx.x;
  if (t >= E8) return;
  int e = t >> 3, h = t & 7;
  int dd = dstv[e];
  float m = funkey(seg_max[dd * 8 + h]);
  atomicAdd(&seg_sum[dd * 8 + h], __expf(a[t] - m));
}

// ---------- scatter att-weighted inst_emb into z = d_out ----------
__global__ __launch_bounds__(256)
void scatter_kernel(const float* __restrict__ inst_emb, const float* __restrict__ a,
                    const unsigned int* __restrict__ seg_max, const float* __restrict__ seg_sum,
                    const int* __restrict__ dstv, float* __restrict__ out, int E) {
  const int wid = (blockIdx.x * blockDim.x + threadIdx.x) >> 6;
  const int lane = threadIdx.x & 63;
  if (wid >= E) return;
  int dd = dstv[wid];
  float iv = inst_emb[wid * D + lane];
#pragma unroll
  for (int h = 0; h < 8; h++) {
    float m = funkey(seg_max[dd * 8 + h]);
    float s = seg_sum[dd * 8 + h];
    float att = __expf(a[wid * 8 + h] - m) / s;
    atomicAdd(&out[dd * 512 + h * 64 + lane], att * iv);
  }
}

// ---------- in-place per-(n,h) transform: row = inst_w_h @ row ----------
__global__ __launch_bounds__(256)
void head_transform_kernel(const float* __restrict__ T_iw, float* __restrict__ out, int NH) {
  const int wid = (blockIdx.x * blockDim.x + threadIdx.x) >> 6;
  const int lane = threadIdx.x & 63;
  if (wid >= NH) return;
  const int h = wid & 7;
  float z = out[wid * D + lane];
  float acc = 0.f;
#pragma unroll 4
  for (int i = 0; i < 64; i++)
    acc = fmaf(bcast(z, i), T_iw[i * 512 + h * 64 + lane], acc);
  out[wid * D + lane] = acc;
}

extern "C" void kernel_launch(void* const* d_in, const int* in_sizes, int n_in,
                              void* d_out, int out_size, void* d_ws, size_t ws_size,
                              hipStream_t stream) {
  const float* features   = (const float*)d_in[0];
  const float* pos_emb    = (const float*)d_in[1];
  const float* self_in_w  = (const float*)d_in[2];
  const float* self_in_b  = (const float*)d_in[3];
  const float* self_out_w = (const float*)d_in[4];
  const float* self_out_b = (const float*)d_in[5];
  const float* cross_in_w = (const float*)d_in[6];
  const float* cross_in_b = (const float*)d_in[7];
  const float* cross_out_w= (const float*)d_in[8];
  const float* cross_out_b= (const float*)d_in[9];
  const float* sa_ln1_g = (const float*)d_in[10];
  const float* sa_ln1_b = (const float*)d_in[11];
  const float* sa_ln2_g = (const float*)d_in[12];
  const float* sa_ln2_b = (const float*)d_in[13];
  const float* ca_ln1_g = (const float*)d_in[14];
  const float* ca_ln1_b = (const float*)d_in[15];
  const float* ca_ln2_g = (const float*)d_in[16];
  const float* ca_ln2_b = (const float*)d_in[17];
  const float* sa_ff_w1 = (const float*)d_in[18];
  const float* sa_ff_b1 = (const float*)d_in[19];
  const float* sa_ff_w2 = (const float*)d_in[20];
  const float* sa_ff_b2 = (const float*)d_in[21];
  const float* ca_ff_w1 = (const float*)d_in[22];
  const float* ca_ff_b1 = (const float*)d_in[23];
  const float* ca_ff_w2 = (const float*)d_in[24];
  const float* ca_ff_b2 = (const float*)d_in[25];
  const float* inst_w   = (const float*)d_in[26];
  const float* attn_vec = (const float*)d_in[27];
  const int* midx = (const int*)d_in[28];
  const int* dstv = (const int*)d_in[29];

  const int N = in_sizes[0] / 64;
  const int E = in_sizes[29];

  // workspace layout (floats): wT[131072] | inst_emb[E*64] | a[E*8] | seg_max[N*8] | seg_sum[N*8]
  float* wT = (float*)d_ws;
  float* inst_emb = wT + 131072;
  float* a_arr = inst_emb + (size_t)E * 64;
  unsigned int* seg_max = (unsigned int*)(a_arr + (size_t)E * 8);
  float* seg_sum = (float*)(seg_max + (size_t)N * 8);

  // zero output and segment buffers (seg_max key 0 == "minus infinity")
  {
    int n4 = out_size / 4;
    zero_kernel<<<(n4 + 255) / 256, 256, 0, stream>>>((float4*)d_out, n4);
    int s4 = (N * 16) / 4;  // seg_max + seg_sum contiguous
    zero_kernel<<<(s4 + 255) / 256, 256, 0, stream>>>((float4*)seg_max, s4);
  }

  transpose_kernel<<<(131072 + 255) / 256, 256, 0, stream>>>(
      self_in_w, self_out_w, sa_ff_w1, sa_ff_w2, cross_in_w, cross_out_w, ca_ff_w1, ca_ff_w2,
      inst_w, wT);

  edge_kernel<<<(E + 3) / 4, 256, 0, stream>>>(
      features, pos_emb, self_in_b, self_out_b, cross_in_b, cross_out_b, sa_ln1_g, sa_ln1_b,
      sa_ln2_g, sa_ln2_b, ca_ln1_g, ca_ln1_b, ca_ln2_g, ca_ln2_b, sa_ff_b1, sa_ff_b2, ca_ff_b1,
      ca_ff_b2, attn_vec, midx, dstv, wT, inst_emb, a_arr, seg_max, E, N);

  expsum_kernel<<<(E * 8 + 255) / 256, 256, 0, stream>>>(a_arr, dstv, seg_max, seg_sum, E * 8);

  scatter_kernel<<<(E + 3) / 4, 256, 0, stream>>>(inst_emb, a_arr, seg_max, seg_sum, dstv,
                                                  (float*)d_out, E);

  head_transform_kernel<<<((N * 8) + 3) / 4, 256, 0, stream>>>(wT + 98304, (float*)d_out, N * 8);
}

// Round 2
// 2327.534 us; speedup vs baseline: 1.3459x; 1.3459x over previous
//
#include <hip/hip_runtime.h>
#include <math.h>

#define SEQ 5
#define D 64
#define B 4

typedef float vf4 __attribute__((ext_vector_type(4)));

// ---------- wave helpers ----------
__device__ __forceinline__ float bcast(float x, int i) {
  return __int_as_float(__builtin_amdgcn_readlane(__float_as_int(x), i));
}
__device__ __forceinline__ float wred64(float x) {
#pragma unroll
  for (int off = 32; off; off >>= 1) x += __shfl_xor(x, off);
  return x;
}
__device__ __forceinline__ float hred8(float x) {
  x += __shfl_xor(x, 1);
  x += __shfl_xor(x, 2);
  x += __shfl_xor(x, 4);
  return x;
}
__device__ __forceinline__ float lnorm2(float t, float g, float b) {
  float m = wred64(t) * 0.015625f;
  float c = t - m;
  float v = wred64(c * c) * 0.015625f;
  return c * rsqrtf(v + 1e-5f) * g + b;
}
__device__ __forceinline__ float gelu(float x) {
  return 0.5f * x * (1.0f + erff(x * 0.70710678118654752440f));
}
// monotonic unsigned key encoding for float atomicMax
__device__ __forceinline__ unsigned int fkey(float f) {
  unsigned int b = __float_as_uint(f);
  return (b & 0x80000000u) ? ~b : (b | 0x80000000u);
}
__device__ __forceinline__ float funkey(unsigned int k) {
  return __uint_as_float((k & 0x80000000u) ? (k ^ 0x80000000u) : ~k);
}

// ---------- zero fill ----------
__global__ void zero_kernel(float4* __restrict__ p, int n4) {
  int t = blockIdx.x * blockDim.x + threadIdx.x;
  if (t < n4) p[t] = make_float4(0.f, 0.f, 0.f, 0.f);
}

// ---------- transpose + 4-wide k-pack all weight matrices into d_ws ----------
// For a src matrix W[C_out][K] (row-major), dst holds, at float offset
//   base + (k>>2)*(4*R) + c*4 + (k&3)        (R = C_out)
// i.e. vf4 P[k4*R + c] = { W[c][4k4], W[c][4k4+1], W[c][4k4+2], W[c][4k4+3] }.
// bases (element offsets):
//   T_si  @ 0      K=64  R=192   self_in_w
//   T_so  @ 12288  K=64  R=64    self_out_w
//   T_w1s @ 16384  K=64  R=256   sa_ff_w1
//   T_w2s @ 32768  K=256 R=64    sa_ff_w2
//   T_ci  @ 49152  K=64  R=192   cross_in_w
//   T_co  @ 61440  K=64  R=64    cross_out_w
//   T_w1c @ 65536  K=64  R=256   ca_ff_w1
//   T_w2c @ 81920  K=256 R=64    ca_ff_w2
//   T_iw  @ 98304  K=64  R=512   inst_w
__global__ void transpose_kernel(const float* __restrict__ si, const float* __restrict__ so,
                                 const float* __restrict__ w1s, const float* __restrict__ w2s,
                                 const float* __restrict__ ci, const float* __restrict__ co,
                                 const float* __restrict__ w1c, const float* __restrict__ w2c,
                                 const float* __restrict__ iw, float* __restrict__ wT) {
  int t = blockIdx.x * blockDim.x + threadIdx.x;
  const float* src;
  int base, R, cs;  // cs = log2(K)
  if      (t < 12288)  { src = si;  base = 0;     R = 192; cs = 6; }
  else if (t < 16384)  { src = so;  base = 12288; R = 64;  cs = 6; }
  else if (t < 32768)  { src = w1s; base = 16384; R = 256; cs = 6; }
  else if (t < 49152)  { src = w2s; base = 32768; R = 64;  cs = 8; }
  else if (t < 61440)  { src = ci;  base = 49152; R = 192; cs = 6; }
  else if (t < 65536)  { src = co;  base = 61440; R = 64;  cs = 6; }
  else if (t < 81920)  { src = w1c; base = 65536; R = 256; cs = 6; }
  else if (t < 98304)  { src = w2c; base = 81920; R = 64;  cs = 8; }
  else if (t < 131072) { src = iw;  base = 98304; R = 512; cs = 6; }
  else return;
  int l = t - base;
  int c = l >> cs;
  int k = l & ((1 << cs) - 1);
  wT[base + (k >> 2) * (R * 4) + c * 4 + (k & 3)] = src[l];
}

// ---------- batched FF block: x[B](LNed) -> 256 hidden (gelu) -> 64, added to acc ----------
__device__ __forceinline__ void ffn_batch(const float (&xln)[B], float (&acc)[B], int lane,
                                          const float* __restrict__ T1,
                                          const float* __restrict__ T2,
                                          const float* __restrict__ b1,
                                          const float* __restrict__ b2) {
  float h[4][B];
  {
    float bb0 = b1[lane], bb1 = b1[64 + lane], bb2 = b1[128 + lane], bb3 = b1[192 + lane];
#pragma unroll
    for (int e = 0; e < B; e++) { h[0][e] = bb0; h[1][e] = bb1; h[2][e] = bb2; h[3][e] = bb3; }
  }
  const vf4* P1 = (const vf4*)T1;
  for (int k4 = 0; k4 < 16; k4++) {
    vf4 w0 = P1[k4 * 256 + lane];
    vf4 w1 = P1[k4 * 256 + 64 + lane];
    vf4 w2 = P1[k4 * 256 + 128 + lane];
    vf4 w3 = P1[k4 * 256 + 192 + lane];
#pragma unroll
    for (int u = 0; u < 4; u++) {
#pragma unroll
      for (int e = 0; e < B; e++) {
        float xi = bcast(xln[e], k4 * 4 + u);
        h[0][e] = fmaf(xi, w0[u], h[0][e]);
        h[1][e] = fmaf(xi, w1[u], h[1][e]);
        h[2][e] = fmaf(xi, w2[u], h[2][e]);
        h[3][e] = fmaf(xi, w3[u], h[3][e]);
      }
    }
  }
#pragma unroll
  for (int r = 0; r < 4; r++)
#pragma unroll
    for (int e = 0; e < B; e++) h[r][e] = gelu(h[r][e]);
  float out[B];
  {
    float ob = b2[lane];
#pragma unroll
    for (int e = 0; e < B; e++) out[e] = ob;
  }
  const vf4* P2 = (const vf4*)T2;
  for (int i4 = 0; i4 < 16; i4++) {
    vf4 wr0 = P2[(0 * 16 + i4) * 64 + lane];
    vf4 wr1 = P2[(1 * 16 + i4) * 64 + lane];
    vf4 wr2 = P2[(2 * 16 + i4) * 64 + lane];
    vf4 wr3 = P2[(3 * 16 + i4) * 64 + lane];
#pragma unroll
    for (int u = 0; u < 4; u++) {
      int i = i4 * 4 + u;
#pragma unroll
      for (int e = 0; e < B; e++) {
        out[e] = fmaf(bcast(h[0][e], i), wr0[u], out[e]);
        out[e] = fmaf(bcast(h[1][e], i), wr1[u], out[e]);
        out[e] = fmaf(bcast(h[2][e], i), wr2[u], out[e]);
        out[e] = fmaf(bcast(h[3][e], i), wr3[u], out[e]);
      }
    }
  }
#pragma unroll
  for (int e = 0; e < B; e++) acc[e] += out[e];
}

// ---------- the per-edge transformer: one wave = B edges, lane = channel ----------
__global__ __launch_bounds__(256)
void edge_kernel(const float* __restrict__ features, const float* __restrict__ pos_emb,
                 const float* __restrict__ self_in_b, const float* __restrict__ self_out_b,
                 const float* __restrict__ cross_in_b, const float* __restrict__ cross_out_b,
                 const float* __restrict__ sa_ln1_g, const float* __restrict__ sa_ln1_b,
                 const float* __restrict__ sa_ln2_g, const float* __restrict__ sa_ln2_b,
                 const float* __restrict__ ca_ln1_g, const float* __restrict__ ca_ln1_b,
                 const float* __restrict__ ca_ln2_g, const float* __restrict__ ca_ln2_b,
                 const float* __restrict__ sa_ff_b1, const float* __restrict__ sa_ff_b2,
                 const float* __restrict__ ca_ff_b1, const float* __restrict__ ca_ff_b2,
                 const float* __restrict__ attn_vec,
                 const int* __restrict__ midx, const int* __restrict__ dstv,
                 const float* __restrict__ wT,
                 float* __restrict__ inst_out, float* __restrict__ a_out,
                 unsigned int* __restrict__ seg_max, int E, int N) {
  const int wid = (blockIdx.x * blockDim.x + threadIdx.x) >> 6;
  const int lane = threadIdx.x & 63;
  const int e0 = wid * B;
  if (e0 >= E) return;

  const float* T_si  = wT;
  const float* T_so  = wT + 12288;
  const float* T_w1s = wT + 16384;
  const float* T_w2s = wT + 32768;
  const float* T_ci  = wT + 49152;
  const float* T_co  = wT + 61440;
  const float* T_w1c = wT + 65536;
  const float* T_w2c = wT + 81920;
  const float* T_iw  = wT + 98304;

  bool ev[B];
  int ids[B][SEQ];
  bool val[B][SEQ];
#pragma unroll
  for (int e = 0; e < B; e++) {
    ev[e] = (e0 + e) < E;
#pragma unroll
    for (int s = 0; s < SEQ; s++) {
      ids[e][s] = ev[e] ? midx[(e0 + e) * SEQ + s] : N;
      val[e][s] = ids[e][s] != N;
    }
  }

  // gather + positional embedding
  float tok[B][SEQ];
  {
    float pe[SEQ];
#pragma unroll
    for (int s = 0; s < SEQ; s++) pe[s] = pos_emb[s * D + lane];
#pragma unroll
    for (int e = 0; e < B; e++)
#pragma unroll
      for (int s = 0; s < SEQ; s++)
        tok[e][s] = val[e][s] ? features[(size_t)ids[e][s] * D + lane] + pe[s] : 0.0f;
  }

  // ---- self-attention (pre-LN) ----
  float x[B][SEQ];
  {
    float g = sa_ln1_g[lane], b = sa_ln1_b[lane];
#pragma unroll
    for (int e = 0; e < B; e++)
#pragma unroll
      for (int s = 0; s < SEQ; s++) x[e][s] = lnorm2(tok[e][s], g, b);
  }

  float q[B][SEQ], k[B][SEQ], v[B][SEQ];
  {
    float bq = self_in_b[lane], bk = self_in_b[64 + lane], bv = self_in_b[128 + lane];
#pragma unroll
    for (int e = 0; e < B; e++)
#pragma unroll
      for (int s = 0; s < SEQ; s++) { q[e][s] = bq; k[e][s] = bk; v[e][s] = bv; }
  }
  {
    const vf4* P = (const vf4*)T_si;
    for (int k4 = 0; k4 < 16; k4++) {
      vf4 wq = P[k4 * 192 + lane];
      vf4 wk = P[k4 * 192 + 64 + lane];
      vf4 wv = P[k4 * 192 + 128 + lane];
#pragma unroll
      for (int u = 0; u < 4; u++) {
        int i = k4 * 4 + u;
#pragma unroll
        for (int e = 0; e < B; e++)
#pragma unroll
          for (int s = 0; s < SEQ; s++) {
            float xi = bcast(x[e][s], i);
            q[e][s] = fmaf(xi, wq[u], q[e][s]);
            k[e][s] = fmaf(xi, wk[u], k[e][s]);
            v[e][s] = fmaf(xi, wv[u], v[e][s]);
          }
      }
    }
  }

  const float scale = 0.35355339059327373f;  // 1/sqrt(dh=8)
  float o[B][SEQ];
#pragma unroll
  for (int e = 0; e < B; e++) {
#pragma unroll
    for (int qs = 0; qs < SEQ; qs++) {
      float at[SEQ];
#pragma unroll
      for (int ks = 0; ks < SEQ; ks++) {
        float p = hred8(q[e][qs] * k[e][ks]) * scale;
        at[ks] = val[e][ks] ? p : -1e9f;
      }
      float m = at[0];
#pragma unroll
      for (int ks = 1; ks < SEQ; ks++) m = fmaxf(m, at[ks]);
      float sum = 0.f;
#pragma unroll
      for (int ks = 0; ks < SEQ; ks++) { at[ks] = __expf(at[ks] - m); sum += at[ks]; }
      float r = 1.0f / sum;
      float acc = 0.f;
#pragma unroll
      for (int ks = 0; ks < SEQ; ks++) acc = fmaf(at[ks] * r, v[e][ks], acc);
      o[e][qs] = acc;
    }
  }

  // out-projection + residual
  {
    float y[B][SEQ];
    float ob = self_out_b[lane];
#pragma unroll
    for (int e = 0; e < B; e++)
#pragma unroll
      for (int s = 0; s < SEQ; s++) y[e][s] = ob;
    const vf4* P = (const vf4*)T_so;
    for (int k4 = 0; k4 < 16; k4++) {
      vf4 w = P[k4 * 64 + lane];
#pragma unroll
      for (int u = 0; u < 4; u++) {
        int i = k4 * 4 + u;
#pragma unroll
        for (int e = 0; e < B; e++)
#pragma unroll
          for (int s = 0; s < SEQ; s++) y[e][s] = fmaf(bcast(o[e][s], i), w[u], y[e][s]);
      }
    }
#pragma unroll
    for (int e = 0; e < B; e++)
#pragma unroll
      for (int s = 0; s < SEQ; s++) tok[e][s] += y[e][s];
  }

  // ---- masked mean pool ----
  float inst[B], nv[B];
#pragma unroll
  for (int e = 0; e < B; e++) {
    float n = 0.f, acc = 0.f;
#pragma unroll
    for (int s = 0; s < SEQ; s++)
      if (val[e][s]) { n += 1.f; acc += tok[e][s]; }
    nv[e] = n;
    inst[e] = acc / fmaxf(n, 1.0f);
  }

  // ---- sa FF ----
  {
    float xln[B];
    float g = sa_ln2_g[lane], b = sa_ln2_b[lane];
#pragma unroll
    for (int e = 0; e < B; e++) xln[e] = lnorm2(inst[e], g, b);
    ffn_batch(xln, inst, lane, T_w1s, T_w2s, sa_ff_b1, sa_ff_b2);
  }

  // ---- cross attention: LN(last-node feat) attends over post-SA tokens ----
  {
    float qx[B];
    {
      float g = ca_ln1_g[lane], b = ca_ln1_b[lane];
#pragma unroll
      for (int e = 0; e < B; e++) {
        int lp = (int)nv[e] - 1;
        if (lp < 0) lp = 0;
        int lid = ev[e] ? midx[(e0 + e) * SEQ + lp] : N;
        float tf = (lid != N) ? features[(size_t)lid * D + lane] : 0.0f;
        qx[e] = lnorm2(tf, g, b);
      }
    }
    float q2[B], k2[B][SEQ], v2[B][SEQ];
    {
      float bq = cross_in_b[lane], bk = cross_in_b[64 + lane], bv = cross_in_b[128 + lane];
#pragma unroll
      for (int e = 0; e < B; e++) {
        q2[e] = bq;
#pragma unroll
        for (int s = 0; s < SEQ; s++) { k2[e][s] = bk; v2[e][s] = bv; }
      }
    }
    const vf4* P = (const vf4*)T_ci;
    for (int k4 = 0; k4 < 16; k4++) {
      vf4 wq = P[k4 * 192 + lane];
      vf4 wk = P[k4 * 192 + 64 + lane];
      vf4 wv = P[k4 * 192 + 128 + lane];
#pragma unroll
      for (int u = 0; u < 4; u++) {
        int i = k4 * 4 + u;
#pragma unroll
        for (int e = 0; e < B; e++) {
          q2[e] = fmaf(bcast(qx[e], i), wq[u], q2[e]);
#pragma unroll
          for (int s = 0; s < SEQ; s++) {
            float ti = bcast(tok[e][s], i);
            k2[e][s] = fmaf(ti, wk[u], k2[e][s]);
            v2[e][s] = fmaf(ti, wv[u], v2[e][s]);
          }
        }
      }
    }
    float o2[B];
#pragma unroll
    for (int e = 0; e < B; e++) {
      float sc[SEQ];
#pragma unroll
      for (int s = 0; s < SEQ; s++) {
        float p = hred8(q2[e] * k2[e][s]) * scale;
        sc[s] = val[e][s] ? p : -1e9f;
      }
      float m = sc[0];
#pragma unroll
      for (int s = 1; s < SEQ; s++) m = fmaxf(m, sc[s]);
      float sum = 0.f;
#pragma unroll
      for (int s = 0; s < SEQ; s++) { sc[s] = __expf(sc[s] - m); sum += sc[s]; }
      float r = 1.0f / sum;
      float acc = 0.f;
#pragma unroll
      for (int s = 0; s < SEQ; s++) acc = fmaf(sc[s] * r, v2[e][s], acc);
      o2[e] = acc;
    }
    // cross out-projection
    {
      float y[B];
      float ob = cross_out_b[lane];
#pragma unroll
      for (int e = 0; e < B; e++) y[e] = ob;
      const vf4* Pc = (const vf4*)T_co;
      for (int k4 = 0; k4 < 16; k4++) {
        vf4 w = Pc[k4 * 64 + lane];
#pragma unroll
        for (int u = 0; u < 4; u++) {
          int i = k4 * 4 + u;
#pragma unroll
          for (int e = 0; e < B; e++) y[e] = fmaf(bcast(o2[e], i), w[u], y[e]);
        }
      }
#pragma unroll
      for (int e = 0; e < B; e++) inst[e] += y[e];
    }
  }

  // ---- ca FF ----
  {
    float xln[B];
    float g = ca_ln2_g[lane], b = ca_ln2_b[lane];
#pragma unroll
    for (int e = 0; e < B; e++) xln[e] = lnorm2(inst[e], g, b);
    ffn_batch(xln, inst, lane, T_w1c, T_w2c, ca_ff_b1, ca_ff_b2);
  }

#pragma unroll
  for (int e = 0; e < B; e++)
    if (ev[e]) inst_out[(size_t)(e0 + e) * D + lane] = inst[e];

  // ---- eft (heads proj) + leaky-relu score + seg_max atomic ----
  float ef[8][B];
#pragma unroll
  for (int r = 0; r < 8; r++)
#pragma unroll
    for (int e = 0; e < B; e++) ef[r][e] = 0.f;
  {
    const vf4* P = (const vf4*)T_iw;
    for (int k4 = 0; k4 < 16; k4++) {
      vf4 w[8];
#pragma unroll
      for (int r = 0; r < 8; r++) w[r] = P[k4 * 512 + r * 64 + lane];
#pragma unroll
      for (int u = 0; u < 4; u++) {
        int i = k4 * 4 + u;
#pragma unroll
        for (int e = 0; e < B; e++) {
          float xi = bcast(inst[e], i);
#pragma unroll
          for (int r = 0; r < 8; r++) ef[r][e] = fmaf(xi, w[r][u], ef[r][e]);
        }
      }
    }
  }
  {
    float av[8];
#pragma unroll
    for (int r = 0; r < 8; r++) av[r] = attn_vec[r * 64 + lane];
#pragma unroll
    for (int e = 0; e < B; e++) {
      if (!ev[e]) continue;
      int dd = dstv[e0 + e];
#pragma unroll
      for (int r = 0; r < 8; r++) {
        float ar = wred64(ef[r][e] * av[r]);
        ar = ar > 0.f ? ar : 0.01f * ar;  // leaky relu
        if (lane == r) {
          a_out[(e0 + e) * 8 + r] = ar;
          atomicMax(&seg_max[dd * 8 + r], fkey(ar));
        }
      }
    }
  }
}

// ---------- edge softmax denominator ----------
__global__ void expsum_kernel(const float* __restrict__ a, const int* __restrict__ dstv,
                              const unsigned int* __restrict__ seg_max,
                              float* __restrict__ seg_sum, int E8) {
  int t = blockIdx.x * blockDim.x + threadIdx.x;
  if (t >= E8) return;
  int e = t >> 3, h = t & 7;
  int dd = dstv[e];
  float m = funkey(seg_max[dd * 8 + h]);
  atomicAdd(&seg_sum[dd * 8 + h], __expf(a[t] - m));
}

// ---------- scatter att-weighted inst_emb into z = d_out ----------
__global__ __launch_bounds__(256)
void scatter_kernel(const float* __restrict__ inst_emb, const float* __restrict__ a,
                    const unsigned int* __restrict__ seg_max, const float* __restrict__ seg_sum,
                    const int* __restrict__ dstv, float* __restrict__ out, int E) {
  const int wid = (blockIdx.x * blockDim.x + threadIdx.x) >> 6;
  const int lane = threadIdx.x & 63;
  if (wid >= E) return;
  int dd = dstv[wid];
  float iv = inst_emb[(size_t)wid * D + lane];
#pragma unroll
  for (int h = 0; h < 8; h++) {
    float m = funkey(seg_max[dd * 8 + h]);
    float s = seg_sum[dd * 8 + h];
    float att = __expf(a[wid * 8 + h] - m) / s;
    atomicAdd(&out[(size_t)dd * 512 + h * 64 + lane], att * iv);
  }
}

// ---------- in-place per-(n,h) transform: row = inst_w_h @ row, 4 nodes per wave ----------
__global__ __launch_bounds__(256)
void head_transform_kernel(const float* __restrict__ T_iw, float* __restrict__ out, int N) {
  const int wid = (blockIdx.x * blockDim.x + threadIdx.x) >> 6;
  const int lane = threadIdx.x & 63;
  const int h = wid & 7;
  const int n0 = (wid >> 3) * 4;
  if (n0 >= N) return;
  float z[4], acc[4];
#pragma unroll
  for (int j = 0; j < 4; j++) {
    z[j] = (n0 + j < N) ? out[((size_t)(n0 + j) * 8 + h) * D + lane] : 0.f;
    acc[j] = 0.f;
  }
  const vf4* P = (const vf4*)T_iw;
  for (int k4 = 0; k4 < 16; k4++) {
    vf4 w = P[k4 * 512 + h * 64 + lane];
#pragma unroll
    for (int u = 0; u < 4; u++) {
      int i = k4 * 4 + u;
#pragma unroll
      for (int j = 0; j < 4; j++) acc[j] = fmaf(bcast(z[j], i), w[u], acc[j]);
    }
  }
#pragma unroll
  for (int j = 0; j < 4; j++)
    if (n0 + j < N) out[((size_t)(n0 + j) * 8 + h) * D + lane] = acc[j];
}

extern "C" void kernel_launch(void* const* d_in, const int* in_sizes, int n_in,
                              void* d_out, int out_size, void* d_ws, size_t ws_size,
                              hipStream_t stream) {
  const float* features   = (const float*)d_in[0];
  const float* pos_emb    = (const float*)d_in[1];
  const float* self_in_w  = (const float*)d_in[2];
  const float* self_in_b  = (const float*)d_in[3];
  const float* self_out_w = (const float*)d_in[4];
  const float* self_out_b = (const float*)d_in[5];
  const float* cross_in_w = (const float*)d_in[6];
  const float* cross_in_b = (const float*)d_in[7];
  const float* cross_out_w= (const float*)d_in[8];
  const float* cross_out_b= (const float*)d_in[9];
  const float* sa_ln1_g = (const float*)d_in[10];
  const float* sa_ln1_b = (const float*)d_in[11];
  const float* sa_ln2_g = (const float*)d_in[12];
  const float* sa_ln2_b = (const float*)d_in[13];
  const float* ca_ln1_g = (const float*)d_in[14];
  const float* ca_ln1_b = (const float*)d_in[15];
  const float* ca_ln2_g = (const float*)d_in[16];
  const float* ca_ln2_b = (const float*)d_in[17];
  const float* sa_ff_w1 = (const float*)d_in[18];
  const float* sa_ff_b1 = (const float*)d_in[19];
  const float* sa_ff_w2 = (const float*)d_in[20];
  const float* sa_ff_b2 = (const float*)d_in[21];
  const float* ca_ff_w1 = (const float*)d_in[22];
  const float* ca_ff_b1 = (const float*)d_in[23];
  const float* ca_ff_w2 = (const float*)d_in[24];
  const float* ca_ff_b2 = (const float*)d_in[25];
  const float* inst_w   = (const float*)d_in[26];
  const float* attn_vec = (const float*)d_in[27];
  const int* midx = (const int*)d_in[28];
  const int* dstv = (const int*)d_in[29];

  const int N = in_sizes[0] / 64;
  const int E = in_sizes[29];

  // workspace layout (floats): wT[131072] | inst_emb[E*64] | a[E*8] | seg_max[N*8] | seg_sum[N*8]
  float* wT = (float*)d_ws;
  float* inst_emb = wT + 131072;
  float* a_arr = inst_emb + (size_t)E * 64;
  unsigned int* seg_max = (unsigned int*)(a_arr + (size_t)E * 8);
  float* seg_sum = (float*)(seg_max + (size_t)N * 8);

  // zero output and segment buffers (seg_max key 0 == "minus infinity")
  {
    int n4 = out_size / 4;
    zero_kernel<<<(n4 + 255) / 256, 256, 0, stream>>>((float4*)d_out, n4);
    int s4 = (N * 16) / 4;  // seg_max + seg_sum contiguous
    zero_kernel<<<(s4 + 255) / 256, 256, 0, stream>>>((float4*)seg_max, s4);
  }

  transpose_kernel<<<(131072 + 255) / 256, 256, 0, stream>>>(
      self_in_w, self_out_w, sa_ff_w1, sa_ff_w2, cross_in_w, cross_out_w, ca_ff_w1, ca_ff_w2,
      inst_w, wT);

  int nwave = (E + B - 1) / B;
  edge_kernel<<<(nwave + 3) / 4, 256, 0, stream>>>(
      features, pos_emb, self_in_b, self_out_b, cross_in_b, cross_out_b, sa_ln1_g, sa_ln1_b,
      sa_ln2_g, sa_ln2_b, ca_ln1_g, ca_ln1_b, ca_ln2_g, ca_ln2_b, sa_ff_b1, sa_ff_b2, ca_ff_b1,
      ca_ff_b2, attn_vec, midx, dstv, wT, inst_emb, a_arr, seg_max, E, N);

  expsum_kernel<<<(E * 8 + 255) / 256, 256, 0, stream>>>(a_arr, dstv, seg_max, seg_sum, E * 8);

  scatter_kernel<<<(E + 3) / 4, 256, 0, stream>>>(inst_emb, a_arr, seg_max, seg_sum, dstv,
                                                  (float*)d_out, E);

  int hwave = ((N + 3) / 4) * 8;
  head_transform_kernel<<<(hwave + 3) / 4, 256, 0, stream>>>(wT + 98304, (float*)d_out, N);
}

// Round 4
// 1793.265 us; speedup vs baseline: 1.7469x; 1.2979x over previous
//
#include <hip/hip_runtime.h>
#include <math.h>

#define D 64
#define LOG2E 1.44269504088896340736f
#define QSCALE (0.35355339059327373f * LOG2E)

typedef float vf4 __attribute__((ext_vector_type(4)));
typedef float f32x4 __attribute__((ext_vector_type(4)));
typedef short bf16x8 __attribute__((ext_vector_type(8)));
typedef unsigned short ushort_t;

// ---------- helpers ----------
__device__ __forceinline__ float bcast(float x, int i) {
  return __int_as_float(__builtin_amdgcn_readlane(__float_as_int(x), i));
}
__device__ __forceinline__ float hr16(float x) {  // sum over 16-lane group
  x += __shfl_xor(x, 1); x += __shfl_xor(x, 2); x += __shfl_xor(x, 4); x += __shfl_xor(x, 8);
  return x;
}
__device__ __forceinline__ ushort_t f2b(float f) {  // fp32 -> bf16 RTNE
  unsigned int u = __float_as_uint(f);
  unsigned int r = (u + 0x7FFFu + ((u >> 16) & 1u)) >> 16;
  return (ushort_t)r;
}
__device__ __forceinline__ float b2f(short s) {  // bf16 -> fp32
  return __uint_as_float(((unsigned int)(unsigned short)s) << 16);
}
__device__ __forceinline__ int bpermI(int addr, int v) {
  return __builtin_amdgcn_ds_bpermute(addr, v);
}
// monotonic unsigned key encoding for float atomicMax
__device__ __forceinline__ unsigned int fkey(float f) {
  unsigned int b = __float_as_uint(f);
  return (b & 0x80000000u) ? ~b : (b | 0x80000000u);
}
__device__ __forceinline__ float funkey(unsigned int k) {
  return __uint_as_float((k & 0x80000000u) ? (k ^ 0x80000000u) : ~k);
}
// XOR-swizzled LDS indexing (rows of 64 bf16 = 8 x 16B units)
__device__ __forceinline__ int swz64(int row, int c) {
  int u = c >> 3; u = (u ^ row) & 7; return row * 64 + (u << 3) + (c & 7);
}
__device__ __forceinline__ int swzu64(int row, int u) {  // bf16x8-unit index
  return row * 8 + ((u ^ row) & 7);
}
__device__ __forceinline__ int swz256(int row, int c) {  // 256-wide rows (FF hidden)
  int u = c >> 3; u = (u & ~7) | ((u ^ row) & 7); return row * 256 + (u << 3) + (c & 7);
}
__device__ __forceinline__ int swzu256(int row, int u) {
  return row * 32 + ((u & ~7) | ((u ^ row) & 7));
}

// ---------- zero fill ----------
__global__ void zero_kernel(float4* __restrict__ p, int n4) {
  int t = blockIdx.x * blockDim.x + threadIdx.x;
  if (t < n4) p[t] = make_float4(0.f, 0.f, 0.f, 0.f);
}

// ---------- prep: pack weights ----------
// ws float layout: [0..32767] T_iw fp32 (k4-packed, head_transform); [32768..33279] u[8][64] fp32;
// (ws+33280) as ushort: bf16 B-frag-packed weights:
//   SI@0 SO@12288 W1S@16384 W2S@32768 CI@49152 CO@61440 W1C@65536 W2C@81920 (end 98304)
// B-frag packing for W[C][K] row-major: frag=(ks*(C/16)+Nt), lane=((k>>3)&3)*16+(c&15), j=k&7
__global__ void prep_kernel(const float* __restrict__ si, const float* __restrict__ so,
                            const float* __restrict__ w1s, const float* __restrict__ w2s,
                            const float* __restrict__ ci, const float* __restrict__ co,
                            const float* __restrict__ w1c, const float* __restrict__ w2c,
                            const float* __restrict__ iw, const float* __restrict__ av,
                            float* __restrict__ ws) {
  int t = blockIdx.x * blockDim.x + threadIdx.x;
  ushort_t* bw = (ushort_t*)(ws + 33280);
  if (t < 98304) {
    const float* src; int base, cs, C; int l = t;
    if      (l < 12288) { src = si;  base = 0;     cs = 6; C = 192; }
    else if (l < 16384) { src = so;  base = 12288; cs = 6; C = 64;  l -= 12288; }
    else if (l < 32768) { src = w1s; base = 16384; cs = 6; C = 256; l -= 16384; }
    else if (l < 49152) { src = w2s; base = 32768; cs = 8; C = 64;  l -= 32768; }
    else if (l < 61440) { src = ci;  base = 49152; cs = 6; C = 192; l -= 49152; }
    else if (l < 65536) { src = co;  base = 61440; cs = 6; C = 64;  l -= 61440; }
    else if (l < 81920) { src = w1c; base = 65536; cs = 6; C = 256; l -= 65536; }
    else                { src = w2c; base = 81920; cs = 8; C = 64;  l -= 81920; }
    int c = l >> cs, k = l & ((1 << cs) - 1);
    int Nt = c >> 4, ks = k >> 5, ll = ((k >> 3) & 3) * 16 + (c & 15), j = k & 7;
    int NT = C >> 4;
    bw[base + (ks * NT + Nt) * 512 + ll * 8 + j] = f2b(src[l]);
  } else if (t < 131072) {
    int l = t - 98304;  // T_iw fp32 k-packed: c 0..511, k 0..63
    int c = l >> 6, k = l & 63;
    ws[(k >> 2) * 2048 + c * 4 + (k & 3)] = iw[l];
  } else if (t < 131584) {
    int l = t - 131072; int h = l >> 6, k = l & 63;
    float acc = 0.f;
    for (int c = 0; c < 64; c++) acc += av[h * 64 + c] * iw[(h * 64 + c) * 64 + k];
    ws[32768 + h * 64 + k] = acc;
  }
}

// ---------- batched FF block on 16-edge inst (C-layout [Nt][rr]) ----------
__device__ __forceinline__ void ffn_mfma(float (&inst)[4][4],
    const float* __restrict__ lng, const float* __restrict__ lnb,
    const bf16x8* __restrict__ W1, const bf16x8* __restrict__ W2,
    const float* __restrict__ fb1, const float* __restrict__ fb2,
    ushort_t* __restrict__ KB, int lane, int quad, int lo) {
  float g[4], bb[4];
#pragma unroll
  for (int nt = 0; nt < 4; nt++) { g[nt] = lng[lo + 16 * nt]; bb[nt] = lnb[lo + 16 * nt]; }
#pragma unroll
  for (int rr = 0; rr < 4; rr++) {
    float s1 = inst[0][rr] + inst[1][rr] + inst[2][rr] + inst[3][rr];
    s1 = hr16(s1);
    float mean = s1 * 0.015625f;
    float s2 = inst[0][rr]*inst[0][rr] + inst[1][rr]*inst[1][rr] + inst[2][rr]*inst[2][rr] + inst[3][rr]*inst[3][rr];
    s2 = hr16(s2);
    float var = s2 * 0.015625f - mean * mean;
    float rs = rsqrtf(var + 1e-5f);
#pragma unroll
    for (int nt = 0; nt < 4; nt++) {
      float x = (inst[nt][rr] - mean) * rs * g[nt] + bb[nt];
      KB[swz64(4 * quad + rr, lo + 16 * nt)] = f2b(x);
    }
  }
  const bf16x8* KBv = (const bf16x8*)KB;
  bf16x8 a0 = KBv[swzu64(lo, quad)];
  bf16x8 a1 = KBv[swzu64(lo, 4 + quad)];
  float H[16][4];
#pragma unroll
  for (int nt = 0; nt < 16; nt++) {
    f32x4 c = {0.f, 0.f, 0.f, 0.f};
    c = __builtin_amdgcn_mfma_f32_16x16x32_bf16(a0, W1[nt * 64 + lane], c, 0, 0, 0);
    c = __builtin_amdgcn_mfma_f32_16x16x32_bf16(a1, W1[(16 + nt) * 64 + lane], c, 0, 0, 0);
    float b1v = fb1[lo + 16 * nt];
#pragma unroll
    for (int rr = 0; rr < 4; rr++) {
      float x = c[rr] + b1v;
      H[nt][rr] = 0.5f * x * (1.0f + erff(x * 0.70710678118654752440f));
    }
  }
#pragma unroll
  for (int nt = 0; nt < 16; nt++)
#pragma unroll
    for (int rr = 0; rr < 4; rr++)
      KB[1024 + swz256(4 * quad + rr, lo + 16 * nt)] = f2b(H[nt][rr]);
  f32x4 acc[4];
#pragma unroll
  for (int nt = 0; nt < 4; nt++) acc[nt] = (f32x4){0.f, 0.f, 0.f, 0.f};
#pragma unroll
  for (int ks = 0; ks < 8; ks++) {
    bf16x8 a = KBv[128 + swzu256(lo, ks * 4 + quad)];
#pragma unroll
    for (int nt = 0; nt < 4; nt++)
      acc[nt] = __builtin_amdgcn_mfma_f32_16x16x32_bf16(a, W2[(ks * 4 + nt) * 64 + lane], acc[nt], 0, 0, 0);
  }
#pragma unroll
  for (int nt = 0; nt < 4; nt++) {
    float b2v = fb2[lo + 16 * nt];
#pragma unroll
    for (int rr = 0; rr < 4; rr++) inst[nt][rr] += acc[nt][rr] + b2v;
  }
}

// ---------- per-edge transformer: one wave = 16 edges; MFMA GEMMs + per-head VALU attention ----
// LDS per wave: XA 80 rows (tokens -> V -> attn-out), KB 160 rows (K rows 0-79, Q rows 80-159)
__global__ __launch_bounds__(128)
void edge_kernel(const float* __restrict__ features, const float* __restrict__ pos_emb,
                 const float* __restrict__ self_in_b, const float* __restrict__ self_out_b,
                 const float* __restrict__ cross_in_b, const float* __restrict__ cross_out_b,
                 const float* __restrict__ sa_ln1_g, const float* __restrict__ sa_ln1_b,
                 const float* __restrict__ sa_ln2_g, const float* __restrict__ sa_ln2_b,
                 const float* __restrict__ ca_ln1_g, const float* __restrict__ ca_ln1_b,
                 const float* __restrict__ ca_ln2_g, const float* __restrict__ ca_ln2_b,
                 const float* __restrict__ sa_ff_b1, const float* __restrict__ sa_ff_b2,
                 const float* __restrict__ ca_ff_b1, const float* __restrict__ ca_ff_b2,
                 const int* __restrict__ midx, const int* __restrict__ dstv,
                 const float* __restrict__ ws,
                 float* __restrict__ inst_out, float* __restrict__ a_out,
                 unsigned int* __restrict__ seg_max, int E, int N) {
  __shared__ __align__(16) ushort_t XA_all[2][5120];
  __shared__ __align__(16) ushort_t KB_all[2][10240];
  const int wv = threadIdx.x >> 6;
  const int lane = threadIdx.x & 63;
  const int wid = blockIdx.x * 2 + wv;
  const int e0 = wid * 16;
  if (e0 >= E) return;
  const int quad = lane >> 4, lo = lane & 15;
  ushort_t* XA = XA_all[wv];
  ushort_t* KB = KB_all[wv];
  const bf16x8* XAv = (const bf16x8*)XA;
  const bf16x8* KBv = (const bf16x8*)KB;

  const ushort_t* bw = (const ushort_t*)(ws + 33280);
  const bf16x8* WSI = (const bf16x8*)(bw);
  const bf16x8* WSO = (const bf16x8*)(bw + 12288);
  const bf16x8* W1S = (const bf16x8*)(bw + 16384);
  const bf16x8* W2S = (const bf16x8*)(bw + 32768);
  const bf16x8* WCI = (const bf16x8*)(bw + 49152);
  const bf16x8* WCO = (const bf16x8*)(bw + 61440);
  const bf16x8* W1C = (const bf16x8*)(bw + 65536);
  const bf16x8* W2C = (const bf16x8*)(bw + 81920);
  const float* uvec = ws + 32768;

  // bpermute byte-addresses of the lane holding edge e=4*quad+r (lane 20*quad+r)
  int ba[4];
#pragma unroll
  for (int r = 0; r < 4; r++) ba[r] = (20 * quad + r) * 4;

  // per-lane edge data (this lane's edge = lo)
  const bool ge = (e0 + lo) < E;
  const int eIdx = min(e0 + lo, E - 1);
  int ids[5];
#pragma unroll
  for (int s = 0; s < 5; s++) ids[s] = midx[eIdx * 5 + s];
  int vb = 0;
#pragma unroll
  for (int s = 0; s < 5; s++) if (ids[s] != N && ge) vb |= (1 << s);
  const int nv = __popc(vb);
  const int lp = max(nv - 1, 0);
  int lid = ids[0];
#pragma unroll
  for (int s = 1; s < 5; s++) lid = (lp == s) ? ids[s] : lid;

  // bpermuted copies for the 4 reg-slot edges of this lane's quad group
  int idsP[4][5], vbP[4], lidP[4];
#pragma unroll
  for (int r = 0; r < 4; r++) {
#pragma unroll
    for (int s = 0; s < 5; s++) idsP[r][s] = bpermI(ba[r], ids[s]);
    vbP[r] = bpermI(ba[r], vb);
    lidP[r] = bpermI(ba[r], lid);
  }

  int ch[4];
#pragma unroll
  for (int nt = 0; nt < 4; nt++) ch[nt] = lo + 16 * nt;

  // ---- stage 1: gather + pos + LN(sa_ln1) -> XA (bf16, s-major rows) ----
  {
    float g[4], bb[4];
#pragma unroll
    for (int nt = 0; nt < 4; nt++) { g[nt] = sa_ln1_g[ch[nt]]; bb[nt] = sa_ln1_b[ch[nt]]; }
#pragma unroll
    for (int s = 0; s < 5; s++) {
      float pv[4];
#pragma unroll
      for (int nt = 0; nt < 4; nt++) pv[nt] = pos_emb[s * 64 + ch[nt]];
      float t[4][4];
#pragma unroll
      for (int r = 0; r < 4; r++) {
        int id = idsP[r][s];
        bool vd = (vbP[r] >> s) & 1;
        const float* fp = features + (size_t)min(id, N - 1) * 64;
#pragma unroll
        for (int nt = 0; nt < 4; nt++) t[nt][r] = vd ? (fp[ch[nt]] + pv[nt]) : 0.f;
      }
#pragma unroll
      for (int r = 0; r < 4; r++) {
        float s1 = t[0][r] + t[1][r] + t[2][r] + t[3][r];
        s1 = hr16(s1);
        float mean = s1 * 0.015625f;
        float s2 = t[0][r]*t[0][r] + t[1][r]*t[1][r] + t[2][r]*t[2][r] + t[3][r]*t[3][r];
        s2 = hr16(s2);
        float var = s2 * 0.015625f - mean * mean;
        float rs = rsqrtf(var + 1e-5f);
#pragma unroll
        for (int nt = 0; nt < 4; nt++) {
          float x = (t[nt][r] - mean) * rs * g[nt] + bb[nt];
          XA[swz64(16 * s + 4 * quad + r, ch[nt])] = f2b(x);
        }
      }
    }
  }

  // ---- stage 2: QKV GEMM; Q(scaled)->KB rows 80+, K->KB rows 0-79, V->XA in place ----
  {
    float qkvb[12];
#pragma unroll
    for (int nt = 0; nt < 12; nt++) qkvb[nt] = self_in_b[16 * nt + lo];
#pragma unroll
    for (int Mt = 0; Mt < 5; Mt++) {
      bf16x8 a0 = XAv[swzu64(16 * Mt + lo, quad)];
      bf16x8 a1 = XAv[swzu64(16 * Mt + lo, 4 + quad)];
#pragma unroll
      for (int Nt = 0; Nt < 12; Nt++) {
        f32x4 c = {0.f, 0.f, 0.f, 0.f};
        c = __builtin_amdgcn_mfma_f32_16x16x32_bf16(a0, WSI[Nt * 64 + lane], c, 0, 0, 0);
        c = __builtin_amdgcn_mfma_f32_16x16x32_bf16(a1, WSI[(12 + Nt) * 64 + lane], c, 0, 0, 0);
        float bias = qkvb[Nt];
        if (Nt < 4) {
#pragma unroll
          for (int rr = 0; rr < 4; rr++)
            KB[swz64(80 + 16 * Mt + 4 * quad + rr, lo + 16 * Nt)] = f2b((c[rr] + bias) * QSCALE);
        } else if (Nt < 8) {
#pragma unroll
          for (int rr = 0; rr < 4; rr++)
            KB[swz64(16 * Mt + 4 * quad + rr, lo + 16 * (Nt - 4))] = f2b(c[rr] + bias);
        } else {
#pragma unroll
          for (int rr = 0; rr < 4; rr++)
            XA[swz64(16 * Mt + 4 * quad + rr, lo + 16 * (Nt - 8))] = f2b(c[rr] + bias);
        }
      }
    }
  }

  // ---- stage 3: PER-HEAD attention; lane=(e=lo, h=quad+4*r2); Q/K from KB, V from XA ----
  // r2=0 writes attn-out into XA units with bit2==row-bit2; r2=1 reads V from complement units.
#pragma unroll
  for (int r2 = 0; r2 < 2; r2++) {
    const int h = quad + 4 * r2;
    float kf[5][8];
#pragma unroll
    for (int ks = 0; ks < 5; ks++) {
      bf16x8 t = KBv[swzu64(16 * ks + lo, h)];
#pragma unroll
      for (int d = 0; d < 8; d++) kf[ks][d] = b2f(t[d]);
    }
    float p[5][5];
#pragma unroll
    for (int qs = 0; qs < 5; qs++) {
      bf16x8 t = KBv[swzu64(80 + 16 * qs + lo, h)];
      float qf[8];
#pragma unroll
      for (int d = 0; d < 8; d++) qf[d] = b2f(t[d]);
      float sv[5];
#pragma unroll
      for (int ks = 0; ks < 5; ks++) {
        float acc = 0.f;
#pragma unroll
        for (int d = 0; d < 8; d++) acc = fmaf(qf[d], kf[ks][d], acc);
        sv[ks] = ((vb >> ks) & 1) ? acc : -1e30f;
      }
      float m = fmaxf(fmaxf(fmaxf(sv[0], sv[1]), fmaxf(sv[2], sv[3])), sv[4]);
      float sum = 0.f;
#pragma unroll
      for (int ks = 0; ks < 5; ks++) { p[qs][ks] = exp2f(sv[ks] - m); sum += p[qs][ks]; }
      float ri = 1.0f / sum;
#pragma unroll
      for (int ks = 0; ks < 5; ks++) p[qs][ks] *= ri;
    }
    float vf[5][8];
#pragma unroll
    for (int ks = 0; ks < 5; ks++) {
      bf16x8 t = XAv[swzu64(16 * ks + lo, h)];
#pragma unroll
      for (int d = 0; d < 8; d++) vf[ks][d] = b2f(t[d]);
    }
#pragma unroll
    for (int qs = 0; qs < 5; qs++) {
      bf16x8 pk;
#pragma unroll
      for (int d = 0; d < 8; d++) {
        float o = 0.f;
#pragma unroll
        for (int ks = 0; ks < 5; ks++) o = fmaf(p[qs][ks], vf[ks][d], o);
        pk[d] = (short)f2b(o);
      }
      ((bf16x8*)XA)[swzu64(16 * qs + lo, h)] = pk;
    }
  }

  // ---- stage 4: out-proj GEMM + residual(re-gather) + masked pool; tokPost -> XA ----
  float pool[4][4];
#pragma unroll
  for (int nt = 0; nt < 4; nt++)
#pragma unroll
    for (int rr = 0; rr < 4; rr++) pool[nt][rr] = 0.f;
  {
    float sob[4];
#pragma unroll
    for (int nt = 0; nt < 4; nt++) sob[nt] = self_out_b[ch[nt]];
#pragma unroll
    for (int Mt = 0; Mt < 5; Mt++) {
      bf16x8 a0 = XAv[swzu64(16 * Mt + lo, quad)];
      bf16x8 a1 = XAv[swzu64(16 * Mt + lo, 4 + quad)];
      float pv[4];
#pragma unroll
      for (int nt = 0; nt < 4; nt++) pv[nt] = pos_emb[Mt * 64 + ch[nt]];
#pragma unroll
      for (int Nt = 0; Nt < 4; Nt++) {
        f32x4 c = {0.f, 0.f, 0.f, 0.f};
        c = __builtin_amdgcn_mfma_f32_16x16x32_bf16(a0, WSO[Nt * 64 + lane], c, 0, 0, 0);
        c = __builtin_amdgcn_mfma_f32_16x16x32_bf16(a1, WSO[(4 + Nt) * 64 + lane], c, 0, 0, 0);
#pragma unroll
        for (int rr = 0; rr < 4; rr++) {
          int id = idsP[rr][Mt];
          bool vd = (vbP[rr] >> Mt) & 1;
          float f = features[(size_t)min(id, N - 1) * 64 + ch[Nt]];
          float tokr = vd ? (f + pv[Nt]) : 0.f;
          float tp = c[rr] + sob[Nt] + tokr;
          pool[Nt][rr] += vd ? tp : 0.f;
          XA[swz64(16 * Mt + 4 * quad + rr, ch[Nt])] = f2b(tp);
        }
      }
    }
  }

  // ---- inst = pool / nv ----
  float inst[4][4];
#pragma unroll
  for (int rr = 0; rr < 4; rr++) {
    float rn = 1.0f / (float)max(__popc(vbP[rr]), 1);
#pragma unroll
    for (int nt = 0; nt < 4; nt++) inst[nt][rr] = pool[nt][rr] * rn;
  }

  // ---- FF-sa ----
  ffn_mfma(inst, sa_ln2_g, sa_ln2_b, W1S, W2S, sa_ff_b1, sa_ff_b2, KB, lane, quad, lo);

  // ---- cross attention ----
  {
    // target LN(ca_ln1) -> KB rows 80..95
    float g[4], bb[4];
#pragma unroll
    for (int nt = 0; nt < 4; nt++) { g[nt] = ca_ln1_g[ch[nt]]; bb[nt] = ca_ln1_b[ch[nt]]; }
#pragma unroll
    for (int rr = 0; rr < 4; rr++) {
      int id = lidP[rr];
      bool vd = id != N;
      const float* fp = features + (size_t)min(id, N - 1) * 64;
      float t[4];
#pragma unroll
      for (int nt = 0; nt < 4; nt++) t[nt] = vd ? fp[ch[nt]] : 0.f;
      float s1 = t[0] + t[1] + t[2] + t[3];
      s1 = hr16(s1);
      float mean = s1 * 0.015625f;
      float s2 = t[0]*t[0] + t[1]*t[1] + t[2]*t[2] + t[3]*t[3];
      s2 = hr16(s2);
      float var = s2 * 0.015625f - mean * mean;
      float rs = rsqrtf(var + 1e-5f);
#pragma unroll
      for (int nt = 0; nt < 4; nt++)
        KB[swz64(80 + 4 * quad + rr, ch[nt])] = f2b((t[nt] - mean) * rs * g[nt] + bb[nt]);
    }
    float cbias[12];
#pragma unroll
    for (int nt = 0; nt < 12; nt++) cbias[nt] = cross_in_b[16 * nt + lo];
    // q_c GEMM, result (scaled) written back to KB rows 80..95
    {
      bf16x8 a0 = KBv[swzu64(80 + lo, quad)];
      bf16x8 a1 = KBv[swzu64(80 + lo, 4 + quad)];
#pragma unroll
      for (int Nt = 0; Nt < 4; Nt++) {
        f32x4 c = {0.f, 0.f, 0.f, 0.f};
        c = __builtin_amdgcn_mfma_f32_16x16x32_bf16(a0, WCI[Nt * 64 + lane], c, 0, 0, 0);
        c = __builtin_amdgcn_mfma_f32_16x16x32_bf16(a1, WCI[(12 + Nt) * 64 + lane], c, 0, 0, 0);
#pragma unroll
        for (int rr = 0; rr < 4; rr++)
          KB[swz64(80 + 4 * quad + rr, lo + 16 * Nt)] = f2b((c[rr] + cbias[Nt]) * QSCALE);
      }
    }
    // cross k/v GEMM: A = tokPost (XA); k_c -> KB rows 0-79, v_c -> XA in place
#pragma unroll
    for (int s = 0; s < 5; s++) {
      bf16x8 a0 = XAv[swzu64(16 * s + lo, quad)];
      bf16x8 a1 = XAv[swzu64(16 * s + lo, 4 + quad)];
#pragma unroll
      for (int Nt = 4; Nt < 12; Nt++) {
        f32x4 c = {0.f, 0.f, 0.f, 0.f};
        c = __builtin_amdgcn_mfma_f32_16x16x32_bf16(a0, WCI[Nt * 64 + lane], c, 0, 0, 0);
        c = __builtin_amdgcn_mfma_f32_16x16x32_bf16(a1, WCI[(12 + Nt) * 64 + lane], c, 0, 0, 0);
        float bias = cbias[Nt];
        if (Nt < 8) {
#pragma unroll
          for (int rr = 0; rr < 4; rr++)
            KB[swz64(16 * s + 4 * quad + rr, lo + 16 * (Nt - 4))] = f2b(c[rr] + bias);
        } else {
#pragma unroll
          for (int rr = 0; rr < 4; rr++)
            XA[swz64(16 * s + 4 * quad + rr, lo + 16 * (Nt - 8))] = f2b(c[rr] + bias);
        }
      }
    }
    // per-head cross attention (1 query per edge); out -> XA rows 0-15
#pragma unroll
    for (int r2 = 0; r2 < 2; r2++) {
      const int h = quad + 4 * r2;
      bf16x8 tq = KBv[swzu64(80 + lo, h)];
      float qf[8];
#pragma unroll
      for (int d = 0; d < 8; d++) qf[d] = b2f(tq[d]);
      float kf[5][8];
#pragma unroll
      for (int s = 0; s < 5; s++) {
        bf16x8 t = KBv[swzu64(16 * s + lo, h)];
#pragma unroll
        for (int d = 0; d < 8; d++) kf[s][d] = b2f(t[d]);
      }
      float sv[5];
#pragma unroll
      for (int s = 0; s < 5; s++) {
        float acc = 0.f;
#pragma unroll
        for (int d = 0; d < 8; d++) acc = fmaf(qf[d], kf[s][d], acc);
        sv[s] = ((vb >> s) & 1) ? acc : -1e30f;
      }
      float m = fmaxf(fmaxf(fmaxf(sv[0], sv[1]), fmaxf(sv[2], sv[3])), sv[4]);
      float p[5], sum = 0.f;
#pragma unroll
      for (int s = 0; s < 5; s++) { p[s] = exp2f(sv[s] - m); sum += p[s]; }
      float ri = 1.0f / sum;
      float vf[5][8];
#pragma unroll
      for (int s = 0; s < 5; s++) {
        bf16x8 t = XAv[swzu64(16 * s + lo, h)];
#pragma unroll
        for (int d = 0; d < 8; d++) vf[s][d] = b2f(t[d]);
      }
      bf16x8 pk;
#pragma unroll
      for (int d = 0; d < 8; d++) {
        float o = 0.f;
#pragma unroll
        for (int s = 0; s < 5; s++) o = fmaf(p[s] * ri, vf[s][d], o);
        pk[d] = (short)f2b(o);
      }
      ((bf16x8*)XA)[swzu64(lo, h)] = pk;
    }
    // cross out-proj from XA rows 0-15
    {
      bf16x8 a0 = XAv[swzu64(lo, quad)];
      bf16x8 a1 = XAv[swzu64(lo, 4 + quad)];
#pragma unroll
      for (int Nt = 0; Nt < 4; Nt++) {
        f32x4 c = {0.f, 0.f, 0.f, 0.f};
        c = __builtin_amdgcn_mfma_f32_16x16x32_bf16(a0, WCO[Nt * 64 + lane], c, 0, 0, 0);
        c = __builtin_amdgcn_mfma_f32_16x16x32_bf16(a1, WCO[(4 + Nt) * 64 + lane], c, 0, 0, 0);
        float cob = cross_out_b[ch[Nt]];
#pragma unroll
        for (int rr = 0; rr < 4; rr++) inst[Nt][rr] += c[rr] + cob;
      }
    }
  }

  // ---- FF-ca ----
  ffn_mfma(inst, ca_ln2_g, ca_ln2_b, W1C, W2C, ca_ff_b1, ca_ff_b2, KB, lane, quad, lo);

  // ---- store inst_emb ----
#pragma unroll
  for (int rr = 0; rr < 4; rr++) {
    int ee = e0 + 4 * quad + rr;
    if (ee < E) {
#pragma unroll
      for (int nt = 0; nt < 4; nt++)
        inst_out[(size_t)ee * 64 + ch[nt]] = inst[nt][rr];
    }
  }

  // ---- a-scores: a[e][h] = leakyrelu(inst . u_h) + seg_max atomics ----
  {
    float uv[8][4];
#pragma unroll
    for (int h = 0; h < 8; h++)
#pragma unroll
      for (int nt = 0; nt < 4; nt++) uv[h][nt] = uvec[h * 64 + ch[nt]];
#pragma unroll
    for (int rr = 0; rr < 4; rr++) {
      int ee = e0 + 4 * quad + rr;
#pragma unroll
      for (int h = 0; h < 8; h++) {
        float t = inst[0][rr] * uv[h][0];
        t = fmaf(inst[1][rr], uv[h][1], t);
        t = fmaf(inst[2][rr], uv[h][2], t);
        t = fmaf(inst[3][rr], uv[h][3], t);
        t = hr16(t);
        float ar = t > 0.f ? t : 0.01f * t;  // leaky relu
        if (lo == h && ee < E) {
          int dd = dstv[ee];
          a_out[(size_t)ee * 8 + h] = ar;
          atomicMax(&seg_max[dd * 8 + h], fkey(ar));
        }
      }
    }
  }
}

// ---------- edge softmax denominator ----------
__global__ void expsum_kernel(const float* __restrict__ a, const int* __restrict__ dstv,
                              const unsigned int* __restrict__ seg_max,
                              float* __restrict__ seg_sum, int E8) {
  int t = blockIdx.x * blockDim.x + threadIdx.x;
  if (t >= E8) return;
  int e = t >> 3, h = t & 7;
  int dd = dstv[e];
  float m = funkey(seg_max[dd * 8 + h]);
  atomicAdd(&seg_sum[dd * 8 + h], __expf(a[t] - m));
}

// ---------- scatter att-weighted inst_emb into z = d_out ----------
__global__ __launch_bounds__(256)
void scatter_kernel(const float* __restrict__ inst_emb, const float* __restrict__ a,
                    const unsigned int* __restrict__ seg_max, const float* __restrict__ seg_sum,
                    const int* __restrict__ dstv, float* __restrict__ out, int E) {
  const int wid = (blockIdx.x * blockDim.x + threadIdx.x) >> 6;
  const int lane = threadIdx.x & 63;
  if (wid >= E) return;
  int dd = dstv[wid];
  float iv = inst_emb[(size_t)wid * D + lane];
#pragma unroll
  for (int h = 0; h < 8; h++) {
    float m = funkey(seg_max[dd * 8 + h]);
    float s = seg_sum[dd * 8 + h];
    float att = __expf(a[wid * 8 + h] - m) / s;
    atomicAdd(&out[(size_t)dd * 512 + h * 64 + lane], att * iv);
  }
}

// ---------- in-place per-(n,h) transform: row = inst_w_h @ row, 4 nodes per wave ----------
__global__ __launch_bounds__(256)
void head_transform_kernel(const float* __restrict__ T_iw, float* __restrict__ out, int N) {
  const int wid = (blockIdx.x * blockDim.x + threadIdx.x) >> 6;
  const int lane = threadIdx.x & 63;
  const int h = wid & 7;
  const int n0 = (wid >> 3) * 4;
  if (n0 >= N) return;
  float z[4], acc[4];
#pragma unroll
  for (int j = 0; j < 4; j++) {
    z[j] = (n0 + j < N) ? out[((size_t)(n0 + j) * 8 + h) * D + lane] : 0.f;
    acc[j] = 0.f;
  }
  const vf4* P = (const vf4*)T_iw;
  for (int k4 = 0; k4 < 16; k4++) {
    vf4 w = P[k4 * 512 + h * 64 + lane];
#pragma unroll
    for (int u = 0; u < 4; u++) {
      int i = k4 * 4 + u;
#pragma unroll
      for (int j = 0; j < 4; j++) acc[j] = fmaf(bcast(z[j], i), w[u], acc[j]);
    }
  }
#pragma unroll
  for (int j = 0; j < 4; j++)
    if (n0 + j < N) out[((size_t)(n0 + j) * 8 + h) * D + lane] = acc[j];
}

extern "C" void kernel_launch(void* const* d_in, const int* in_sizes, int n_in,
                              void* d_out, int out_size, void* d_ws, size_t ws_size,
                              hipStream_t stream) {
  const float* features   = (const float*)d_in[0];
  const float* pos_emb    = (const float*)d_in[1];
  const float* self_in_w  = (const float*)d_in[2];
  const float* self_in_b  = (const float*)d_in[3];
  const float* self_out_w = (const float*)d_in[4];
  const float* self_out_b = (const float*)d_in[5];
  const float* cross_in_w = (const float*)d_in[6];
  const float* cross_in_b = (const float*)d_in[7];
  const float* cross_out_w= (const float*)d_in[8];
  const float* cross_out_b= (const float*)d_in[9];
  const float* sa_ln1_g = (const float*)d_in[10];
  const float* sa_ln1_b = (const float*)d_in[11];
  const float* sa_ln2_g = (const float*)d_in[12];
  const float* sa_ln2_b = (const float*)d_in[13];
  const float* ca_ln1_g = (const float*)d_in[14];
  const float* ca_ln1_b = (const float*)d_in[15];
  const float* ca_ln2_g = (const float*)d_in[16];
  const float* ca_ln2_b = (const float*)d_in[17];
  const float* sa_ff_w1 = (const float*)d_in[18];
  const float* sa_ff_b1 = (const float*)d_in[19];
  const float* sa_ff_w2 = (const float*)d_in[20];
  const float* sa_ff_b2 = (const float*)d_in[21];
  const float* ca_ff_w1 = (const float*)d_in[22];
  const float* ca_ff_b1 = (const float*)d_in[23];
  const float* ca_ff_w2 = (const float*)d_in[24];
  const float* ca_ff_b2 = (const float*)d_in[25];
  const float* inst_w   = (const float*)d_in[26];
  const float* attn_vec = (const float*)d_in[27];
  const int* midx = (const int*)d_in[28];
  const int* dstv = (const int*)d_in[29];

  const int N = in_sizes[0] / 64;
  const int E = in_sizes[29];

  // ws floats: [0..32767] T_iw | [32768..33279] u | [33280..82431] bf16 weight packs
  //            [131072...] inst_emb[E*64] | a[E*8] | seg_max[N*8] | seg_sum[N*8]
  float* wsf = (float*)d_ws;
  float* inst_emb = wsf + 131072;
  float* a_arr = inst_emb + (size_t)E * 64;
  unsigned int* seg_max = (unsigned int*)(a_arr + (size_t)E * 8);
  float* seg_sum = (float*)(seg_max + (size_t)N * 8);

  {
    int n4 = out_size / 4;
    zero_kernel<<<(n4 + 255) / 256, 256, 0, stream>>>((float4*)d_out, n4);
    int s4 = (N * 16) / 4;  // seg_max + seg_sum contiguous
    zero_kernel<<<(s4 + 255) / 256, 256, 0, stream>>>((float4*)seg_max, s4);
  }

  prep_kernel<<<(131584 + 255) / 256, 256, 0, stream>>>(
      self_in_w, self_out_w, sa_ff_w1, sa_ff_w2, cross_in_w, cross_out_w, ca_ff_w1, ca_ff_w2,
      inst_w, attn_vec, wsf);

  int nblk = (E + 31) / 32;  // 2 waves/block, 16 edges/wave
  edge_kernel<<<nblk, 128, 0, stream>>>(
      features, pos_emb, self_in_b, self_out_b, cross_in_b, cross_out_b, sa_ln1_g, sa_ln1_b,
      sa_ln2_g, sa_ln2_b, ca_ln1_g, ca_ln1_b, ca_ln2_g, ca_ln2_b, sa_ff_b1, sa_ff_b2, ca_ff_b1,
      ca_ff_b2, midx, dstv, wsf, inst_emb, a_arr, seg_max, E, N);

  expsum_kernel<<<(E * 8 + 255) / 256, 256, 0, stream>>>(a_arr, dstv, seg_max, seg_sum, E * 8);

  scatter_kernel<<<(E + 3) / 4, 256, 0, stream>>>(inst_emb, a_arr, seg_max, seg_sum, dstv,
                                                  (float*)d_out, E);

  int hwave = ((N + 3) / 4) * 8;
  head_transform_kernel<<<(hwave + 3) / 4, 256, 0, stream>>>(wsf, (float*)d_out, N);
}

// Round 5
// 1028.228 us; speedup vs baseline: 3.0467x; 1.7440x over previous
//
#include <hip/hip_runtime.h>
#include <math.h>

#define D 64
#define LOG2E 1.44269504088896340736f
#define QSCALE (0.35355339059327373f * LOG2E)

typedef float f32x4 __attribute__((ext_vector_type(4)));
typedef float vf4 __attribute__((ext_vector_type(4)));
typedef short bf16x8 __attribute__((ext_vector_type(8)));
typedef unsigned short ushort_t;

#define MF(a, b, c) __builtin_amdgcn_mfma_f32_16x16x32_bf16(a, b, c, 0, 0, 0)

// ---------- helpers ----------
__device__ __forceinline__ float bcast(float x, int i) {
  return __int_as_float(__builtin_amdgcn_readlane(__float_as_int(x), i));
}
__device__ __forceinline__ float qsum(float x) {  // sum over the 4 quads (lanes lo, lo+16, lo+32, lo+48)
  x += __shfl_xor(x, 16);
  x += __shfl_xor(x, 32);
  return x;
}
__device__ __forceinline__ ushort_t f2b(float f) {  // fp32 -> bf16 RTNE
  unsigned int u = __float_as_uint(f);
  unsigned int r = (u + 0x7FFFu + ((u >> 16) & 1u)) >> 16;
  return (ushort_t)r;
}
__device__ __forceinline__ float b2f(short s) {  // bf16 -> fp32
  return __uint_as_float(((unsigned int)(unsigned short)s) << 16);
}
__device__ __forceinline__ f32x4 ld4(const float* __restrict__ p) { return *(const f32x4*)p; }
// monotonic unsigned key encoding for float atomicMax
__device__ __forceinline__ unsigned int fkey(float f) {
  unsigned int b = __float_as_uint(f);
  return (b & 0x80000000u) ? ~b : (b | 0x80000000u);
}
__device__ __forceinline__ float funkey(unsigned int k) {
  return __uint_as_float((k & 0x80000000u) ? (k ^ 0x80000000u) : ~k);
}
// pack two C-tiles (even ct, odd ct) into one x32 B-operand pair
__device__ __forceinline__ bf16x8 mkpair(const f32x4& ce, const f32x4& co) {
  bf16x8 b;
#pragma unroll
  for (int j = 0; j < 4; j++) {
    b[j] = (short)f2b(ce[j]);
    b[4 + j] = (short)f2b(co[j]);
  }
  return b;
}
__device__ __forceinline__ f32x4 unpk(bf16x8 p, int half) {  // half 0 = even ct, 1 = odd ct
  f32x4 r;
#pragma unroll
  for (int j = 0; j < 4; j++) r[j] = b2f(p[half * 4 + j]);
  return r;
}

// transposed-layout LayerNorm: x,y are 16 channel values/lane (4 ct-tiles x 4 rr); stats over 64 ch
__device__ __forceinline__ void lnT(const f32x4 (&x)[4], f32x4 (&y)[4],
                                    const float* __restrict__ g, const float* __restrict__ b,
                                    int quad) {
  float s1 = 0.f, s2 = 0.f;
#pragma unroll
  for (int ct = 0; ct < 4; ct++)
#pragma unroll
    for (int r = 0; r < 4; r++) { s1 += x[ct][r]; s2 += x[ct][r] * x[ct][r]; }
  s1 = qsum(s1);
  s2 = qsum(s2);
  float mean = s1 * 0.015625f;
  float var = s2 * 0.015625f - mean * mean;
  float rs = rsqrtf(var + 1e-5f);
#pragma unroll
  for (int ct = 0; ct < 4; ct++) {
    f32x4 gv = ld4(g + 16 * ct + 4 * quad);
    f32x4 bv = ld4(b + 16 * ct + 4 * quad);
#pragma unroll
    for (int r = 0; r < 4; r++) y[ct][r] = (x[ct][r] - mean) * rs * gv[r] + bv[r];
  }
}

// ---------- zero fill ----------
__global__ void zero_kernel(float4* __restrict__ p, int n4) {
  int t = blockIdx.x * blockDim.x + threadIdx.x;
  if (t < n4) p[t] = make_float4(0.f, 0.f, 0.f, 0.f);
}

// ---------- prep: pack weights as x32 A-frags with the k-slot permutation ----------
// ws float layout: [0..32767] T_iw fp32 (k4-packed, head_transform); [32768..33279] u[8][64];
// (ws+33280) as ushort: A-frag packs:
//   SI@0 SO@12288 W1S@16384 W2S@32768 CI@49152 CO@61440 W1C@65536 W2C@81920 (end 98304)
// For W[Cout][K]: frag = ct*T + t (ct = c>>4, T = K/32, t = k>>5); within frag:
//   lane = quad*16 + m (m = c&15, quad = (k>>2)&3), j = 4*((k>>4)&1) + (k&3)
//   (so A k-slot(quad,j) <-> channel 32t + 16*(j>>2) + 4*quad + (j&3), matching the B pairs)
__global__ void prep_kernel(const float* __restrict__ si, const float* __restrict__ so,
                            const float* __restrict__ w1s, const float* __restrict__ w2s,
                            const float* __restrict__ ci, const float* __restrict__ co,
                            const float* __restrict__ w1c, const float* __restrict__ w2c,
                            const float* __restrict__ iw, const float* __restrict__ av,
                            float* __restrict__ ws) {
  int t = blockIdx.x * blockDim.x + threadIdx.x;
  ushort_t* bw = (ushort_t*)(ws + 33280);
  if (t < 98304) {
    const float* src;
    int base, cs;
    int l = t;
    if      (l < 12288) { src = si;  base = 0;     cs = 6; }
    else if (l < 16384) { src = so;  base = 12288; cs = 6; l -= 12288; }
    else if (l < 32768) { src = w1s; base = 16384; cs = 6; l -= 16384; }
    else if (l < 49152) { src = w2s; base = 32768; cs = 8; l -= 32768; }
    else if (l < 61440) { src = ci;  base = 49152; cs = 6; l -= 49152; }
    else if (l < 65536) { src = co;  base = 61440; cs = 6; l -= 61440; }
    else if (l < 81920) { src = w1c; base = 65536; cs = 6; l -= 65536; }
    else                { src = w2c; base = 81920; cs = 8; l -= 81920; }
    int c = l >> cs, k = l & ((1 << cs) - 1);
    int T = (1 << cs) >> 5;
    int ct = c >> 4, m = c & 15, tt = k >> 5, rem = k & 31;
    int quad = (rem >> 2) & 3;
    int j = (((rem >> 4) & 1) << 2) | (rem & 3);
    bw[base + (size_t)((ct * T + tt) * 64 + quad * 16 + m) * 8 + j] = f2b(src[l]);
  } else if (t < 131072) {
    int l = t - 98304;  // T_iw fp32 k-packed: c 0..511, k 0..63 (for head_transform)
    int c = l >> 6, k = l & 63;
    ws[(k >> 2) * 2048 + c * 4 + (k & 3)] = iw[l];
  } else if (t < 131584) {
    int l = t - 131072;
    int h = l >> 6, k = l & 63;
    float acc = 0.f;
    for (int c = 0; c < 64; c++) acc += av[h * 64 + c] * iw[(h * 64 + c) * 64 + k];
    ws[32768 + h * 64 + k] = acc;
  }
}

// ---------- transposed FF block: inst (f32, [ch][edge] tiles) += FF(LN(inst)) ----------
__device__ __forceinline__ void ffnT(f32x4 (&inst)[4],
                                     const float* __restrict__ g, const float* __restrict__ b,
                                     const bf16x8* __restrict__ W1, const bf16x8* __restrict__ W2,
                                     const float* __restrict__ b1, const float* __restrict__ b2,
                                     int lane, int quad) {
  f32x4 y[4];
  lnT(inst, y, g, b, quad);
  bf16x8 x0 = mkpair(y[0], y[1]), x1 = mkpair(y[2], y[3]);
  bf16x8 Hp[8];
#pragma unroll
  for (int ht = 0; ht < 8; ht++) {
    f32x4 h[2];
#pragma unroll
    for (int u = 0; u < 2; u++) {
      int ct = 2 * ht + u;
      f32x4 c = {0.f, 0.f, 0.f, 0.f};
      c = MF(W1[(ct * 2 + 0) * 64 + lane], x0, c);
      c = MF(W1[(ct * 2 + 1) * 64 + lane], x1, c);
      f32x4 bb = ld4(b1 + 16 * ct + 4 * quad);
#pragma unroll
      for (int r = 0; r < 4; r++) {
        float v = c[r] + bb[r];
        h[u][r] = 0.5f * v * (1.0f + erff(v * 0.70710678118654752440f));
      }
    }
    Hp[ht] = mkpair(h[0], h[1]);
  }
#pragma unroll
  for (int ct = 0; ct < 4; ct++) {
    f32x4 c = {0.f, 0.f, 0.f, 0.f};
#pragma unroll
    for (int t = 0; t < 8; t++) c = MF(W2[(ct * 8 + t) * 64 + lane], Hp[t], c);
    f32x4 bb = ld4(b2 + 16 * ct + 4 * quad);
#pragma unroll
    for (int r = 0; r < 4; r++) inst[ct][r] += c[r] + bb[r];
  }
}

// ---------- per-edge transformer: one wave = 16 edges, fully register-resident ----------
__global__ __launch_bounds__(64, 2)
void edge_kernel(const float* __restrict__ features, const float* __restrict__ pos_emb,
                 const float* __restrict__ self_in_b, const float* __restrict__ self_out_b,
                 const float* __restrict__ cross_in_b, const float* __restrict__ cross_out_b,
                 const float* __restrict__ sa_ln1_g, const float* __restrict__ sa_ln1_b,
                 const float* __restrict__ sa_ln2_g, const float* __restrict__ sa_ln2_b,
                 const float* __restrict__ ca_ln1_g, const float* __restrict__ ca_ln1_b,
                 const float* __restrict__ ca_ln2_g, const float* __restrict__ ca_ln2_b,
                 const float* __restrict__ sa_ff_b1, const float* __restrict__ sa_ff_b2,
                 const float* __restrict__ ca_ff_b1, const float* __restrict__ ca_ff_b2,
                 const int* __restrict__ midx, const int* __restrict__ dstv,
                 const float* __restrict__ ws,
                 float* __restrict__ inst_out, float* __restrict__ a_out,
                 unsigned int* __restrict__ seg_max, int E, int N) {
  const int lane = threadIdx.x;
  const int quad = lane >> 4, lo = lane & 15;
  const int e0 = blockIdx.x * 16;
  __shared__ float xp[16 * 68];

  const ushort_t* bw = (const ushort_t*)(ws + 33280);
  const bf16x8* WSI = (const bf16x8*)(bw);
  const bf16x8* WSO = (const bf16x8*)(bw + 12288);
  const bf16x8* W1S = (const bf16x8*)(bw + 16384);
  const bf16x8* W2S = (const bf16x8*)(bw + 32768);
  const bf16x8* WCI = (const bf16x8*)(bw + 49152);
  const bf16x8* WCO = (const bf16x8*)(bw + 61440);
  const bf16x8* W1C = (const bf16x8*)(bw + 65536);
  const bf16x8* W2C = (const bf16x8*)(bw + 81920);
  const float* uvec = ws + 32768;

  // per-lane edge meta: lane (quad, lo) owns edge e0+lo (replicated across quads)
  const bool ge = (e0 + lo) < E;
  const int eIdx = min(e0 + lo, E - 1);
  int ids[5];
#pragma unroll
  for (int s = 0; s < 5; s++) ids[s] = midx[eIdx * 5 + s];
  int vb = 0;
#pragma unroll
  for (int s = 0; s < 5; s++)
    if (ids[s] != N && ge) vb |= (1 << s);
  const int nv = __popc(vb);
  const int lp = max(nv - 1, 0);
  int lid = ids[0];
#pragma unroll
  for (int s = 1; s < 5; s++) lid = (lp == s) ? ids[s] : lid;

  // ---- stage 1: gather + pos + LN(sa_ln1) -> XL pairs (bf16, [ch][edge]) ----
  bf16x8 XL[5][2];
#pragma unroll
  for (int s = 0; s < 5; s++) {
    f32x4 t[4], y[4];
    const bool vd = (vb >> s) & 1;
    const float* fp = features + (size_t)min(ids[s], N - 1) * 64;
#pragma unroll
    for (int ct = 0; ct < 4; ct++) {
      f32x4 f = ld4(fp + 16 * ct + 4 * quad);
      f32x4 p = ld4(pos_emb + s * 64 + 16 * ct + 4 * quad);
#pragma unroll
      for (int r = 0; r < 4; r++) t[ct][r] = vd ? (f[r] + p[r]) : 0.f;
    }
    lnT(t, y, sa_ln1_g, sa_ln1_b, quad);
    XL[s][0] = mkpair(y[0], y[1]);
    XL[s][1] = mkpair(y[2], y[3]);
  }

  // ---- K, V GEMMs (register-resident, bf16-packed) ----
  bf16x8 Kp[5][2], Vp[5][2];
#pragma unroll
  for (int s = 0; s < 5; s++) {
    f32x4 kt[4], vt[4];
#pragma unroll
    for (int ct = 0; ct < 4; ct++) {
      f32x4 c = {0.f, 0.f, 0.f, 0.f};
      c = MF(WSI[((4 + ct) * 2 + 0) * 64 + lane], XL[s][0], c);
      c = MF(WSI[((4 + ct) * 2 + 1) * 64 + lane], XL[s][1], c);
      f32x4 bb = ld4(self_in_b + 64 + 16 * ct + 4 * quad);
#pragma unroll
      for (int r = 0; r < 4; r++) kt[ct][r] = c[r] + bb[r];
      f32x4 c2 = {0.f, 0.f, 0.f, 0.f};
      c2 = MF(WSI[((8 + ct) * 2 + 0) * 64 + lane], XL[s][0], c2);
      c2 = MF(WSI[((8 + ct) * 2 + 1) * 64 + lane], XL[s][1], c2);
      f32x4 bb2 = ld4(self_in_b + 128 + 16 * ct + 4 * quad);
#pragma unroll
      for (int r = 0; r < 4; r++) vt[ct][r] = c2[r] + bb2[r];
    }
    Kp[s][0] = mkpair(kt[0], kt[1]);
    Kp[s][1] = mkpair(kt[2], kt[3]);
    Vp[s][0] = mkpair(vt[0], vt[1]);
    Vp[s][1] = mkpair(vt[2], vt[3]);
  }

  // ---- per-qs: Q GEMM, per-head attention (lane-local + 1 shfl), PV, out-proj, residual, pool ----
  f32x4 pool[4];
#pragma unroll
  for (int ct = 0; ct < 4; ct++) pool[ct] = (f32x4){0.f, 0.f, 0.f, 0.f};
  bf16x8 TP[5][2];
#pragma unroll
  for (int qs = 0; qs < 5; qs++) {
    f32x4 qf[4];
#pragma unroll
    for (int ct = 0; ct < 4; ct++) {
      f32x4 c = {0.f, 0.f, 0.f, 0.f};
      c = MF(WSI[(ct * 2 + 0) * 64 + lane], XL[qs][0], c);
      c = MF(WSI[(ct * 2 + 1) * 64 + lane], XL[qs][1], c);
      f32x4 bb = ld4(self_in_b + 16 * ct + 4 * quad);
#pragma unroll
      for (int r = 0; r < 4; r++) qf[ct][r] = (c[r] + bb[r]) * QSCALE;
    }
    // head h = 2ct + (quad>>1): dot over this lane's 4 ch + partner quad via shfl_xor(16)
    float p[4][5];
#pragma unroll
    for (int ct = 0; ct < 4; ct++) {
      float mx = -3.0e30f;
#pragma unroll
      for (int ks = 0; ks < 5; ks++) {
        f32x4 kv = unpk(Kp[ks][ct >> 1], ct & 1);
        float sp = qf[ct][0] * kv[0] + qf[ct][1] * kv[1] + qf[ct][2] * kv[2] + qf[ct][3] * kv[3];
        sp += __shfl_xor(sp, 16);
        float sv = ((vb >> ks) & 1) ? sp : -1e30f;
        p[ct][ks] = sv;
        mx = fmaxf(mx, sv);
      }
      float sum = 0.f;
#pragma unroll
      for (int ks = 0; ks < 5; ks++) { p[ct][ks] = exp2f(p[ct][ks] - mx); sum += p[ct][ks]; }
      float ri = 1.0f / sum;
#pragma unroll
      for (int ks = 0; ks < 5; ks++) p[ct][ks] *= ri;
    }
    f32x4 o[4];
#pragma unroll
    for (int ct = 0; ct < 4; ct++) {
      o[ct] = (f32x4){0.f, 0.f, 0.f, 0.f};
#pragma unroll
      for (int ks = 0; ks < 5; ks++) {
        f32x4 vv = unpk(Vp[ks][ct >> 1], ct & 1);
#pragma unroll
        for (int r = 0; r < 4; r++) o[ct][r] = fmaf(p[ct][ks], vv[r], o[ct][r]);
      }
    }
    bf16x8 o0 = mkpair(o[0], o[1]), o1 = mkpair(o[2], o[3]);
    // out-proj + residual (re-gather) + masked pool; tokPost -> TP pairs
    const bool vd = (vb >> qs) & 1;
    const float* fp = features + (size_t)min(ids[qs], N - 1) * 64;
    f32x4 tpc[4];
#pragma unroll
    for (int ct = 0; ct < 4; ct++) {
      f32x4 c = {0.f, 0.f, 0.f, 0.f};
      c = MF(WSO[(ct * 2 + 0) * 64 + lane], o0, c);
      c = MF(WSO[(ct * 2 + 1) * 64 + lane], o1, c);
      f32x4 bb = ld4(self_out_b + 16 * ct + 4 * quad);
      f32x4 f = ld4(fp + 16 * ct + 4 * quad);
      f32x4 pp = ld4(pos_emb + qs * 64 + 16 * ct + 4 * quad);
#pragma unroll
      for (int r = 0; r < 4; r++) {
        float tokr = vd ? (f[r] + pp[r]) : 0.f;
        float tp = c[r] + bb[r] + tokr;
        tpc[ct][r] = tp;
        pool[ct][r] += vd ? tp : 0.f;
      }
    }
    TP[qs][0] = mkpair(tpc[0], tpc[1]);
    TP[qs][1] = mkpair(tpc[2], tpc[3]);
  }

  f32x4 inst[4];
  {
    float rn = 1.0f / (float)max(nv, 1);
#pragma unroll
    for (int ct = 0; ct < 4; ct++)
#pragma unroll
      for (int r = 0; r < 4; r++) inst[ct][r] = pool[ct][r] * rn;
  }

  // ---- FF-sa ----
  ffnT(inst, sa_ln2_g, sa_ln2_b, W1S, W2S, sa_ff_b1, sa_ff_b2, lane, quad);

  // ---- cross attention ----
  {
    f32x4 tf[4], xq[4];
    const bool vdl = lid != N;
    const float* fp = features + (size_t)min(lid, N - 1) * 64;
#pragma unroll
    for (int ct = 0; ct < 4; ct++) {
      f32x4 f = ld4(fp + 16 * ct + 4 * quad);
#pragma unroll
      for (int r = 0; r < 4; r++) tf[ct][r] = vdl ? f[r] : 0.f;
    }
    lnT(tf, xq, ca_ln1_g, ca_ln1_b, quad);
    bf16x8 xq0 = mkpair(xq[0], xq[1]), xq1 = mkpair(xq[2], xq[3]);
    f32x4 qcf[4];
#pragma unroll
    for (int ct = 0; ct < 4; ct++) {
      f32x4 c = {0.f, 0.f, 0.f, 0.f};
      c = MF(WCI[(ct * 2 + 0) * 64 + lane], xq0, c);
      c = MF(WCI[(ct * 2 + 1) * 64 + lane], xq1, c);
      f32x4 bb = ld4(cross_in_b + 16 * ct + 4 * quad);
#pragma unroll
      for (int r = 0; r < 4; r++) qcf[ct][r] = (c[r] + bb[r]) * QSCALE;
    }
    bf16x8 Kc[5][2], Vc[5][2];
#pragma unroll
    for (int s = 0; s < 5; s++) {
      f32x4 kt[4], vt[4];
#pragma unroll
      for (int ct = 0; ct < 4; ct++) {
        f32x4 c = {0.f, 0.f, 0.f, 0.f};
        c = MF(WCI[((4 + ct) * 2 + 0) * 64 + lane], TP[s][0], c);
        c = MF(WCI[((4 + ct) * 2 + 1) * 64 + lane], TP[s][1], c);
        f32x4 bb = ld4(cross_in_b + 64 + 16 * ct + 4 * quad);
#pragma unroll
        for (int r = 0; r < 4; r++) kt[ct][r] = c[r] + bb[r];
        f32x4 c2 = {0.f, 0.f, 0.f, 0.f};
        c2 = MF(WCI[((8 + ct) * 2 + 0) * 64 + lane], TP[s][0], c2);
        c2 = MF(WCI[((8 + ct) * 2 + 1) * 64 + lane], TP[s][1], c2);
        f32x4 bb2 = ld4(cross_in_b + 128 + 16 * ct + 4 * quad);
#pragma unroll
        for (int r = 0; r < 4; r++) vt[ct][r] = c2[r] + bb2[r];
      }
      Kc[s][0] = mkpair(kt[0], kt[1]);
      Kc[s][1] = mkpair(kt[2], kt[3]);
      Vc[s][0] = mkpair(vt[0], vt[1]);
      Vc[s][1] = mkpair(vt[2], vt[3]);
    }
    float p[4][5];
#pragma unroll
    for (int ct = 0; ct < 4; ct++) {
      float mx = -3.0e30f;
#pragma unroll
      for (int ks = 0; ks < 5; ks++) {
        f32x4 kv = unpk(Kc[ks][ct >> 1], ct & 1);
        float sp = qcf[ct][0] * kv[0] + qcf[ct][1] * kv[1] + qcf[ct][2] * kv[2] + qcf[ct][3] * kv[3];
        sp += __shfl_xor(sp, 16);
        float sv = ((vb >> ks) & 1) ? sp : -1e30f;
        p[ct][ks] = sv;
        mx = fmaxf(mx, sv);
      }
      float sum = 0.f;
#pragma unroll
      for (int ks = 0; ks < 5; ks++) { p[ct][ks] = exp2f(p[ct][ks] - mx); sum += p[ct][ks]; }
      float ri = 1.0f / sum;
#pragma unroll
      for (int ks = 0; ks < 5; ks++) p[ct][ks] *= ri;
    }
    f32x4 co[4];
#pragma unroll
    for (int ct = 0; ct < 4; ct++) {
      co[ct] = (f32x4){0.f, 0.f, 0.f, 0.f};
#pragma unroll
      for (int ks = 0; ks < 5; ks++) {
        f32x4 vv = unpk(Vc[ks][ct >> 1], ct & 1);
#pragma unroll
        for (int r = 0; r < 4; r++) co[ct][r] = fmaf(p[ct][ks], vv[r], co[ct][r]);
      }
    }
    bf16x8 c0 = mkpair(co[0], co[1]), c1 = mkpair(co[2], co[3]);
#pragma unroll
    for (int ct = 0; ct < 4; ct++) {
      f32x4 c = {0.f, 0.f, 0.f, 0.f};
      c = MF(WCO[(ct * 2 + 0) * 64 + lane], c0, c);
      c = MF(WCO[(ct * 2 + 1) * 64 + lane], c1, c);
      f32x4 bb = ld4(cross_out_b + 16 * ct + 4 * quad);
#pragma unroll
      for (int r = 0; r < 4; r++) inst[ct][r] += c[r] + bb[r];
    }
  }

  // ---- FF-ca ----
  ffnT(inst, ca_ln2_g, ca_ln2_b, W1C, W2C, ca_ff_b1, ca_ff_b2, lane, quad);

  // ---- a-scores: a[e][h] = leakyrelu(inst . u_h) ----
  float a8[8];
#pragma unroll
  for (int h = 0; h < 8; h++) {
    float sp = 0.f;
#pragma unroll
    for (int ct = 0; ct < 4; ct++) {
      f32x4 uu = ld4(uvec + h * 64 + 16 * ct + 4 * quad);
#pragma unroll
      for (int r = 0; r < 4; r++) sp = fmaf(inst[ct][r], uu[r], sp);
    }
    sp = qsum(sp);
    a8[h] = sp > 0.f ? sp : 0.01f * sp;
  }
  if (ge) {
    int dd = dstv[e0 + lo];
    float v0 = quad == 0 ? a8[0] : quad == 1 ? a8[2] : quad == 2 ? a8[4] : a8[6];
    float v1 = quad == 0 ? a8[1] : quad == 1 ? a8[3] : quad == 2 ? a8[5] : a8[7];
    atomicMax(&seg_max[dd * 8 + 2 * quad], fkey(v0));
    atomicMax(&seg_max[dd * 8 + 2 * quad + 1], fkey(v1));
    if (quad < 2) {
      f32x4 st = (quad == 0) ? (f32x4){a8[0], a8[1], a8[2], a8[3]}
                             : (f32x4){a8[4], a8[5], a8[6], a8[7]};
      *(f32x4*)(a_out + (size_t)(e0 + lo) * 8 + 4 * quad) = st;
    }
  }

  // ---- inst_out: small LDS transpose ([ch][edge] -> [edge][ch]) + coalesced store ----
#pragma unroll
  for (int ct = 0; ct < 4; ct++)
    *(f32x4*)(&xp[lo * 68 + 16 * ct + 4 * quad]) = inst[ct];
  __syncthreads();
  {
    int er = lane >> 2, cb = (lane & 3) * 16;
    if (e0 + er < E) {
#pragma unroll
      for (int u = 0; u < 4; u++) {
        f32x4 v = *(const f32x4*)(&xp[er * 68 + cb + 4 * u]);
        *(f32x4*)(inst_out + (size_t)(e0 + er) * 64 + cb + 4 * u) = v;
      }
    }
  }
}

// ---------- edge softmax denominator ----------
__global__ void expsum_kernel(const float* __restrict__ a, const int* __restrict__ dstv,
                              const unsigned int* __restrict__ seg_max,
                              float* __restrict__ seg_sum, int E8) {
  int t = blockIdx.x * blockDim.x + threadIdx.x;
  if (t >= E8) return;
  int e = t >> 3, h = t & 7;
  int dd = dstv[e];
  float m = funkey(seg_max[dd * 8 + h]);
  atomicAdd(&seg_sum[dd * 8 + h], __expf(a[t] - m));
}

// ---------- scatter att-weighted inst_emb into z = d_out ----------
__global__ __launch_bounds__(256)
void scatter_kernel(const float* __restrict__ inst_emb, const float* __restrict__ a,
                    const unsigned int* __restrict__ seg_max, const float* __restrict__ seg_sum,
                    const int* __restrict__ dstv, float* __restrict__ out, int E) {
  const int wid = (blockIdx.x * blockDim.x + threadIdx.x) >> 6;
  const int lane = threadIdx.x & 63;
  if (wid >= E) return;
  int dd = dstv[wid];
  float iv = inst_emb[(size_t)wid * D + lane];
#pragma unroll
  for (int h = 0; h < 8; h++) {
    float m = funkey(seg_max[dd * 8 + h]);
    float s = seg_sum[dd * 8 + h];
    float att = __expf(a[wid * 8 + h] - m) / s;
    atomicAdd(&out[(size_t)dd * 512 + h * 64 + lane], att * iv);
  }
}

// ---------- in-place per-(n,h) transform: row = inst_w_h @ row, 4 nodes per wave ----------
__global__ __launch_bounds__(256)
void head_transform_kernel(const float* __restrict__ T_iw, float* __restrict__ out, int N) {
  const int wid = (blockIdx.x * blockDim.x + threadIdx.x) >> 6;
  const int lane = threadIdx.x & 63;
  const int h = wid & 7;
  const int n0 = (wid >> 3) * 4;
  if (n0 >= N) return;
  float z[4], acc[4];
#pragma unroll
  for (int j = 0; j < 4; j++) {
    z[j] = (n0 + j < N) ? out[((size_t)(n0 + j) * 8 + h) * D + lane] : 0.f;
    acc[j] = 0.f;
  }
  const vf4* P = (const vf4*)T_iw;
  for (int k4 = 0; k4 < 16; k4++) {
    vf4 w = P[k4 * 512 + h * 64 + lane];
#pragma unroll
    for (int u = 0; u < 4; u++) {
      int i = k4 * 4 + u;
#pragma unroll
      for (int j = 0; j < 4; j++) acc[j] = fmaf(bcast(z[j], i), w[u], acc[j]);
    }
  }
#pragma unroll
  for (int j = 0; j < 4; j++)
    if (n0 + j < N) out[((size_t)(n0 + j) * 8 + h) * D + lane] = acc[j];
}

extern "C" void kernel_launch(void* const* d_in, const int* in_sizes, int n_in,
                              void* d_out, int out_size, void* d_ws, size_t ws_size,
                              hipStream_t stream) {
  const float* features   = (const float*)d_in[0];
  const float* pos_emb    = (const float*)d_in[1];
  const float* self_in_w  = (const float*)d_in[2];
  const float* self_in_b  = (const float*)d_in[3];
  const float* self_out_w = (const float*)d_in[4];
  const float* self_out_b = (const float*)d_in[5];
  const float* cross_in_w = (const float*)d_in[6];
  const float* cross_in_b = (const float*)d_in[7];
  const float* cross_out_w= (const float*)d_in[8];
  const float* cross_out_b= (const float*)d_in[9];
  const float* sa_ln1_g = (const float*)d_in[10];
  const float* sa_ln1_b = (const float*)d_in[11];
  const float* sa_ln2_g = (const float*)d_in[12];
  const float* sa_ln2_b = (const float*)d_in[13];
  const float* ca_ln1_g = (const float*)d_in[14];
  const float* ca_ln1_b = (const float*)d_in[15];
  const float* ca_ln2_g = (const float*)d_in[16];
  const float* ca_ln2_b = (const float*)d_in[17];
  const float* sa_ff_w1 = (const float*)d_in[18];
  const float* sa_ff_b1 = (const float*)d_in[19];
  const float* sa_ff_w2 = (const float*)d_in[20];
  const float* sa_ff_b2 = (const float*)d_in[21];
  const float* ca_ff_w1 = (const float*)d_in[22];
  const float* ca_ff_b1 = (const float*)d_in[23];
  const float* ca_ff_w2 = (const float*)d_in[24];
  const float* ca_ff_b2 = (const float*)d_in[25];
  const float* inst_w   = (const float*)d_in[26];
  const float* attn_vec = (const float*)d_in[27];
  const int* midx = (const int*)d_in[28];
  const int* dstv = (const int*)d_in[29];

  const int N = in_sizes[0] / 64;
  const int E = in_sizes[29];

  // ws floats: [0..32767] T_iw | [32768..33279] u | [33280..82431] bf16 A-frag packs
  //            [131072...] inst_emb[E*64] | a[E*8] | seg_max[N*8] | seg_sum[N*8]
  float* wsf = (float*)d_ws;
  float* inst_emb = wsf + 131072;
  float* a_arr = inst_emb + (size_t)E * 64;
  unsigned int* seg_max = (unsigned int*)(a_arr + (size_t)E * 8);
  float* seg_sum = (float*)(seg_max + (size_t)N * 8);

  {
    int n4 = out_size / 4;
    zero_kernel<<<(n4 + 255) / 256, 256, 0, stream>>>((float4*)d_out, n4);
    int s4 = (N * 16) / 4;  // seg_max + seg_sum contiguous
    zero_kernel<<<(s4 + 255) / 256, 256, 0, stream>>>((float4*)seg_max, s4);
  }

  prep_kernel<<<(131584 + 255) / 256, 256, 0, stream>>>(
      self_in_w, self_out_w, sa_ff_w1, sa_ff_w2, cross_in_w, cross_out_w, ca_ff_w1, ca_ff_w2,
      inst_w, attn_vec, wsf);

  int nblk = (E + 15) / 16;  // 1 wave/block, 16 edges/wave
  edge_kernel<<<nblk, 64, 0, stream>>>(
      features, pos_emb, self_in_b, self_out_b, cross_in_b, cross_out_b, sa_ln1_g, sa_ln1_b,
      sa_ln2_g, sa_ln2_b, ca_ln1_g, ca_ln1_b, ca_ln2_g, ca_ln2_b, sa_ff_b1, sa_ff_b2, ca_ff_b1,
      ca_ff_b2, midx, dstv, wsf, inst_emb, a_arr, seg_max, E, N);

  expsum_kernel<<<(E * 8 + 255) / 256, 256, 0, stream>>>(a_arr, dstv, seg_max, seg_sum, E * 8);

  scatter_kernel<<<(E + 3) / 4, 256, 0, stream>>>(inst_emb, a_arr, seg_max, seg_sum, dstv,
                                                  (float*)d_out, E);

  int hwave = ((N + 3) / 4) * 8;
  head_transform_kernel<<<(hwave + 3) / 4, 256, 0, stream>>>(wsf, (float*)d_out, N);
}